// Round 17
// baseline (393.858 us; speedup 1.0000x reference)
//
#include <hip/hip_runtime.h>
#include <hip/hip_bf16.h>
#include <math.h>

typedef unsigned short u16;
typedef unsigned int u32;
typedef __attribute__((ext_vector_type(8))) short bf16x8v;
typedef __attribute__((ext_vector_type(4))) float f32x4;

// ---------------- problem constants ----------------
constexpr int NS = 25, NQ = 15, NB = 40;
constexpr int B3 = 375;     // 15*25
constexpr int T49 = 49;
constexpr float BN_INV = 0.9999950000374997f;

// ---------------- workspace layout (BYTES), f32 activations ----------------
constexpr size_t A1_OFF    = 0;            // (40,56,56,32) f32 = 16,056,320
constexpr size_t X2_OFF    = 16056320;     // (40,56,56,64) f32 = 32,112,640
constexpr size_t P2_OFF    = 48168960;     // (40,28,28,64) f32 = 8,028,160
constexpr size_t X3_OFF    = 0;            // (40,28,28,128) f32 = 16,056,320
constexpr size_t P3_OFF    = 56197120;     // (40,14,14,128) f32 = 4,014,080
constexpr size_t X4_OFF    = 16056320;     // (40,14,14,256) f32 = 8,028,160
constexpr size_t FEATT_OFF = 60211200;     // (40,49,256) f32 = 2,007,040
constexpr size_t PROJ_OFF  = 24084480;     // (1960,64) f32 = 501,760
constexpr size_t ATT_OFF   = 24586240;     // (375,49,256) f32 = 18,816,000
constexpr size_t GI_OFF    = 62218240;     // (18375,384) f32 = 28,224,000
constexpr size_t Y0_OFF    = 0;            // (18375,128) f32 = 9,408,000
constexpr size_t HFIN_OFF  = 90442240;     // (375,128) f32 = 192,000
constexpr size_t WBH_OFF   = 91027456;     // bf16-hi arena 649,216 u16
constexpr size_t WBL_OFF   = 92325888;     // bf16-lo arena
// u16-element offsets within each arena:
constexpr size_t W2_E = 0;        // 64*288
constexpr size_t W3_E = 18432;    // 128*576
constexpr size_t W4_E = 92160;    // 256*1152
constexpr size_t AW_E = 387072;   // 64*256
constexpr size_t WI0_E = 403456;  // 384*512
constexpr size_t WI1_E = 600064;  // 384*128

static __device__ __forceinline__ u16 f2b(float f) {
  __hip_bfloat16 h = __float2bfloat16(f);
  return *reinterpret_cast<u16*>(&h);
}
static __device__ __forceinline__ float b2f(u16 u) {
  return __uint_as_float((u32)u << 16);
}
// split v into hi+lo bf16 pair, packed into u32 words
static __device__ __forceinline__ void split8(const float* v, u32* hp, u32* lp) {
  u16 h[8], l[8];
#pragma unroll
  for (int j = 0; j < 8; ++j) {
    const u16 hb = f2b(v[j]);
    h[j] = hb;
    l[j] = f2b(v[j] - b2f(hb));
  }
#pragma unroll
  for (int j = 0; j < 4; ++j) {
    hp[j] = (u32)h[2 * j] | ((u32)h[2 * j + 1] << 16);
    lp[j] = (u32)l[2 * j] | ((u32)l[2 * j + 1] << 16);
  }
}
// fast sigmoid / tanh (exp2+rcp intrinsics; err ~1e-6, validated at absmax 0.0)
constexpr float LOG2E = 1.4426950408889634f;
static __device__ __forceinline__ float fsigmoid(float x) {
  return __builtin_amdgcn_rcpf(1.f + __builtin_amdgcn_exp2f(-x * LOG2E));
}
static __device__ __forceinline__ float ftanh(float x) {
  return 1.f - 2.f * __builtin_amdgcn_rcpf(__builtin_amdgcn_exp2f(x * (2.f * LOG2E)) + 1.f);
}

// ---------------- weight split converters ----------------
__global__ void cvt_split(const float* __restrict__ x, u16* __restrict__ oh,
                          u16* __restrict__ ol, int n) {
  int i = blockIdx.x * 256 + threadIdx.x;
  if (i >= n) return;
  const float v = x[i];
  const u16 h = f2b(v);
  oh[i] = h;
  ol[i] = f2b(v - b2f(h));
}
// OIHW f32 -> [oc][(ky*3+kx)*IC + ic] hi/lo bf16
__global__ void cvt_conv_w_split(const float* __restrict__ w, u16* __restrict__ oh,
                                 u16* __restrict__ ol, int OC, int IC) {
  const int n = OC * IC * 9;
  int i = blockIdx.x * 256 + threadIdx.x;
  if (i >= n) return;
  const int oc = i / (IC * 9), rem = i % (IC * 9);
  const int e = rem / IC, ic = rem % IC;
  const int ky = e / 3, kx = e % 3;
  const float v = w[((size_t)(oc * IC + ic) * 3 + ky) * 3 + kx];
  const u16 h = f2b(v);
  oh[i] = h;
  ol[i] = f2b(v - b2f(h));
}

// ---------------- fused conv1(s2)+BN+ReLU+pool2, f32 out NHWC ----------------
__global__ __launch_bounds__(256) void conv1_pool(
    const float* __restrict__ support, const float* __restrict__ query,
    const float* __restrict__ w1, const float* __restrict__ cb1,
    const float* __restrict__ g1, const float* __restrict__ be1,
    float* __restrict__ out) {
  __shared__ float wl[288], scl[32], shl[32], cbl[32];
  const int tid = threadIdx.x;
  for (int l = tid; l < 288; l += 256) wl[l] = w1[l];  // FIX(r5): strided, 288>256
  if (tid < 32) { scl[tid] = g1[tid] * BN_INV; shl[tid] = be1[tid]; cbl[tid] = cb1[tid]; }
  __syncthreads();
  const int oc = tid & 31;
  const int p = blockIdx.x * 8 + (tid >> 5);   // 0 .. 125439 = (b,oy,ox)
  const int ox = p % 56, oy = (p / 56) % 56, b = p / 3136;
  const float* in_b = (b < NS) ? (support + (size_t)b * 50176)
                               : (query + (size_t)(b - NS) * 50176);
  const int iy0 = 4 * oy - 1, ix0 = 4 * ox - 1;
  float pat[5][5];
#pragma unroll
  for (int dy = 0; dy < 5; ++dy) {
    const int iy = iy0 + dy;
#pragma unroll
    for (int dx = 0; dx < 5; ++dx) {
      const int ix = ix0 + dx;
      pat[dy][dx] = (iy >= 0 && iy < 224 && ix >= 0 && ix < 224)
                        ? in_b[(size_t)iy * 224 + ix] : 0.f;
    }
  }
  const float* wp = &wl[oc * 9];
  float mx = 0.f;  // post-ReLU values >= 0
#pragma unroll
  for (int py = 0; py < 2; ++py)
#pragma unroll
    for (int px = 0; px < 2; ++px) {
      float acc = 0.f;
#pragma unroll
      for (int ky = 0; ky < 3; ++ky)
#pragma unroll
        for (int kx = 0; kx < 3; ++kx)
          acc += pat[2 * py + ky][2 * px + kx] * wp[ky * 3 + kx];
      float v = (acc + cbl[oc]) * scl[oc] + shl[oc];
      mx = fmaxf(mx, v);
    }
  out[(size_t)p * 32 + oc] = mx;
}

// ---------------- f32 NHWC maxpool 2x2 ----------------
__global__ void maxpool2_f32(const float* __restrict__ X, float* __restrict__ Y,
                             int Bn, int H, int W, int C) {
  const int OH = H >> 1, OW = W >> 1;
  const int cpr = C >> 2;
  const int chunks = Bn * OH * OW * cpr;
  for (int i = blockIdx.x * blockDim.x + threadIdx.x; i < chunks;
       i += gridDim.x * blockDim.x) {
    const int c4 = i % cpr, m = i / cpr;
    const int ox = m % OW, oy = (m / OW) % OH, b = m / (OW * OH);
    const size_t base = (((size_t)b * H + 2 * oy) * W + 2 * ox) * C + (c4 << 2);
    const float4 r0 = *(const float4*)&X[base];
    const float4 r1 = *(const float4*)&X[base + C];
    const float4 r2 = *(const float4*)&X[base + (size_t)W * C];
    const float4 r3 = *(const float4*)&X[base + (size_t)W * C + C];
    float4 o;
    o.x = fmaxf(fmaxf(r0.x, r1.x), fmaxf(r2.x, r3.x));
    o.y = fmaxf(fmaxf(r0.y, r1.y), fmaxf(r2.y, r3.y));
    o.z = fmaxf(fmaxf(r0.z, r1.z), fmaxf(r2.z, r3.z));
    o.w = fmaxf(fmaxf(r0.w, r1.w), fmaxf(r2.w, r3.w));
    *(float4*)&Y[(size_t)m * C + (c4 << 2)] = o;
  }
}

// ---------------- split-bf16 MFMA GEMM: C = epi(A @ W^T) --------------------
// 3-pass Dekker: acc += Ah*Wh + Ah*Wl + Al*Wh  (error ~1.6e-5 relative)
// AMODE 0: A f32 (M x K) contiguous.
// AMODE 1: K=512 concat gather: k<256 -> A(=ATT f32), else A2(=FEATT f32) qrep.
// AMODE 2: implicit im2col from A = NHWC f32 (Bn,H,W,IC); K = 9*IC; pad=1.
// EPI 0: f32 out = relu((acc+p0[n])*p1[n]*BN_INV + p2[n]).  EPI 1: f32 out = acc+p0[n].
template <int AMODE, int EPI>
__global__ __launch_bounds__(256) void sgemm(
    const float* __restrict__ A, const float* __restrict__ A2, int M, int K,
    const u16* __restrict__ Bh, const u16* __restrict__ Bl,
    const float* __restrict__ p0, const float* __restrict__ p1,
    const float* __restrict__ p2, float* __restrict__ Cout, int ldc,
    int H, int W, int IC, int icb) {
  __shared__ u16 Ash[64][72], Asl[64][72];
  __shared__ u16 Bsh[64][72], Bsl[64][72];
  const int tid = threadIdx.x;
  const int lane = tid & 63, wv = tid >> 6;
  const int wy = wv >> 1, wx = wv & 1;
  const int n0 = blockIdx.x * 64, m0 = blockIdx.y * 64;
  f32x4 acc[2][2] = {{{0, 0, 0, 0}, {0, 0, 0, 0}}, {{0, 0, 0, 0}, {0, 0, 0, 0}}};
  for (int k0 = 0; k0 < K; k0 += 64) {
    // ---- stage A (split f32 -> hi/lo bf16) ----
#pragma unroll
    for (int s = 0; s < 2; ++s) {
      const int c = s * 256 + tid;
      const int row = c >> 3, kc = (c & 7) << 3;
      const int gm = m0 + row, gk = k0 + kc;
      float4 x0 = {0, 0, 0, 0}, x1 = {0, 0, 0, 0};
      if (AMODE == 0) {
        if (gm < M && gk < K) {
          const float* p = A + (size_t)gm * K + gk;
          x0 = *(const float4*)p; x1 = *(const float4*)(p + 4);
        }
      } else if (AMODE == 1) {
        if (gm < M) {
          const float* p;
          if (gk < 256) {
            p = A + (size_t)gm * 256 + gk;
          } else {
            const int b = gm / T49, t = gm % T49, q = b / NS;
            p = A2 + (((size_t)(NS + q) * T49 + t) << 8) + (gk - 256);
          }
          x0 = *(const float4*)p; x1 = *(const float4*)(p + 4);
        }
      } else {  // implicit im2col
        if (gm < M && gk < K) {
          const int ox = gm % W, t_ = gm / W;
          const int oy = t_ % H, b = t_ / H;
          const int e = gk >> icb, ic = gk & (IC - 1);
          const int ky = e / 3, kx = e - 3 * (e / 3);
          const int iy = oy + ky - 1, ix = ox + kx - 1;
          if (iy >= 0 && iy < H && ix >= 0 && ix < W) {
            const float* p = A + (((size_t)b * H + iy) * W + ix) * IC + ic;
            x0 = *(const float4*)p; x1 = *(const float4*)(p + 4);
          }
        }
      }
      float v[8] = {x0.x, x0.y, x0.z, x0.w, x1.x, x1.y, x1.z, x1.w};
      u32 hp[4], lp[4];
      split8(v, hp, lp);
      *(uint4*)&Ash[row][kc] = *(uint4*)hp;
      *(uint4*)&Asl[row][kc] = *(uint4*)lp;
    }
    // ---- stage B (pre-split weights) ----
#pragma unroll
    for (int s = 0; s < 2; ++s) {
      const int c = s * 256 + tid;
      const int row = c >> 3, kc = (c & 7) << 3;
      const int gk = k0 + kc;
      uint4 vh = {0u, 0u, 0u, 0u}, vl = {0u, 0u, 0u, 0u};
      if (gk < K) {
        vh = *(const uint4*)&Bh[(size_t)(n0 + row) * K + gk];
        vl = *(const uint4*)&Bl[(size_t)(n0 + row) * K + gk];
      }
      *(uint4*)&Bsh[row][kc] = vh;
      *(uint4*)&Bsl[row][kc] = vl;
    }
    __syncthreads();
#pragma unroll
    for (int kk = 0; kk < 64; kk += 32) {
      const int ko = kk + ((lane >> 4) << 3);
      const int ra0 = wy * 32 + (lane & 15), ra1 = ra0 + 16;
      const int rb0 = wx * 32 + (lane & 15), rb1 = rb0 + 16;
      bf16x8v a0h = *(const bf16x8v*)&Ash[ra0][ko];
      bf16x8v a1h = *(const bf16x8v*)&Ash[ra1][ko];
      bf16x8v b0h = *(const bf16x8v*)&Bsh[rb0][ko];
      bf16x8v b1h = *(const bf16x8v*)&Bsh[rb1][ko];
      bf16x8v a0l = *(const bf16x8v*)&Asl[ra0][ko];
      bf16x8v a1l = *(const bf16x8v*)&Asl[ra1][ko];
      bf16x8v b0l = *(const bf16x8v*)&Bsl[rb0][ko];
      bf16x8v b1l = *(const bf16x8v*)&Bsl[rb1][ko];
      acc[0][0] = __builtin_amdgcn_mfma_f32_16x16x32_bf16(a0h, b0h, acc[0][0], 0, 0, 0);
      acc[0][1] = __builtin_amdgcn_mfma_f32_16x16x32_bf16(a0h, b1h, acc[0][1], 0, 0, 0);
      acc[1][0] = __builtin_amdgcn_mfma_f32_16x16x32_bf16(a1h, b0h, acc[1][0], 0, 0, 0);
      acc[1][1] = __builtin_amdgcn_mfma_f32_16x16x32_bf16(a1h, b1h, acc[1][1], 0, 0, 0);
      acc[0][0] = __builtin_amdgcn_mfma_f32_16x16x32_bf16(a0h, b0l, acc[0][0], 0, 0, 0);
      acc[0][1] = __builtin_amdgcn_mfma_f32_16x16x32_bf16(a0h, b1l, acc[0][1], 0, 0, 0);
      acc[1][0] = __builtin_amdgcn_mfma_f32_16x16x32_bf16(a1h, b0l, acc[1][0], 0, 0, 0);
      acc[1][1] = __builtin_amdgcn_mfma_f32_16x16x32_bf16(a1h, b1l, acc[1][1], 0, 0, 0);
      acc[0][0] = __builtin_amdgcn_mfma_f32_16x16x32_bf16(a0l, b0h, acc[0][0], 0, 0, 0);
      acc[0][1] = __builtin_amdgcn_mfma_f32_16x16x32_bf16(a0l, b1h, acc[0][1], 0, 0, 0);
      acc[1][0] = __builtin_amdgcn_mfma_f32_16x16x32_bf16(a1l, b0h, acc[1][0], 0, 0, 0);
      acc[1][1] = __builtin_amdgcn_mfma_f32_16x16x32_bf16(a1l, b1h, acc[1][1], 0, 0, 0);
    }
    __syncthreads();
  }
  // ---- epilogue (f32 out) ----
#pragma unroll
  for (int r = 0; r < 2; ++r) {
#pragma unroll
    for (int c = 0; c < 2; ++c) {
      const int gn = n0 + wx * 32 + c * 16 + (lane & 15);
      float sc0 = 0.f, sh0 = 0.f;
      if (EPI == 0) { sc0 = p1[gn] * BN_INV; sh0 = p2[gn]; }
#pragma unroll
      for (int i = 0; i < 4; ++i) {
        const int gm = m0 + wy * 32 + r * 16 + ((lane >> 4) << 2) + i;
        if (gm >= M) continue;
        const float a = acc[r][c][i];
        if (EPI == 0) {
          Cout[(size_t)gm * ldc + gn] = fmaxf((a + p0[gn]) * sc0 + sh0, 0.f);
        } else {
          Cout[(size_t)gm * ldc + gn] = a + p0[gn];
        }
      }
    }
  }
}

// ---------------- fused attention, block = (q,s,t-group of 7) ---------------
// r10: 256-thread blocks, parallel 8-lane softmax, padded WqT.
__global__ __launch_bounds__(256) void attention_f32(
    const float* __restrict__ proj, const float* __restrict__ featT,
    float* __restrict__ attended) {
  __shared__ float WqT[64][9];    // [h][tloc], 7 used, pad 9 -> conflict-free
  __shared__ float WhT[64][51];   // [h][u], odd pad -> conflict-free
  __shared__ float sc[7][64];
  const int bid = blockIdx.x;
  const int qs = bid / 7, tg = bid - 7 * qs;
  const int q = qs / NS, s = qs - NS * q;
  const int tid = threadIdx.x;
  const float* pq = proj + ((size_t)(NS + q) * T49 + tg * 7) * 64;
  const float* ph = proj + (size_t)s * T49 * 64;
  for (int l = tid; l < 7 * 64; l += 256) WqT[l & 63][l >> 6] = pq[l];
  for (int l = tid; l < T49 * 64; l += 256) WhT[l & 63][l >> 6] = ph[l];
  __syncthreads();
  // scores: 343 (t,u) pairs over 256 threads, 4-acc ILP h-loop
  constexpr float C2LOG2E = 2.8853900817779268f;
  for (int e = tid; e < 343; e += 256) {
    const int tl = e / 49, u = e - 49 * tl;
    float a0 = 0.f, a1 = 0.f, a2 = 0.f, a3 = 0.f;
#pragma unroll
    for (int h = 0; h < 64; h += 4) {
      const float p0 = WqT[h + 0][tl] * WhT[h + 0][u];
      const float p1 = WqT[h + 1][tl] * WhT[h + 1][u];
      const float p2 = WqT[h + 2][tl] * WhT[h + 2][u];
      const float p3 = WqT[h + 3][tl] * WhT[h + 3][u];
      a0 += 1.f - 2.f * __builtin_amdgcn_rcpf(__builtin_amdgcn_exp2f(p0 * C2LOG2E) + 1.f);
      a1 += 1.f - 2.f * __builtin_amdgcn_rcpf(__builtin_amdgcn_exp2f(p1 * C2LOG2E) + 1.f);
      a2 += 1.f - 2.f * __builtin_amdgcn_rcpf(__builtin_amdgcn_exp2f(p2 * C2LOG2E) + 1.f);
      a3 += 1.f - 2.f * __builtin_amdgcn_rcpf(__builtin_amdgcn_exp2f(p3 * C2LOG2E) + 1.f);
    }
    sc[tl][u] = (a0 + a1) + (a2 + a3);
  }
  __syncthreads();
  // parallel softmax: 8 lanes per row, all 56 lanes in wave 0
  if (tid < 56) {
    const int t = tid >> 3, g = tid & 7;
    float m = -3.4e38f;
    for (int u = g; u < T49; u += 8) m = fmaxf(m, sc[t][u]);
    m = fmaxf(m, __shfl_xor(m, 4));
    m = fmaxf(m, __shfl_xor(m, 2));
    m = fmaxf(m, __shfl_xor(m, 1));
    float ssum = 0.f;
    for (int u = g; u < T49; u += 8) {
      const float e = __builtin_amdgcn_exp2f((sc[t][u] - m) * LOG2E);
      sc[t][u] = e; ssum += e;
    }
    ssum += __shfl_xor(ssum, 4);
    ssum += __shfl_xor(ssum, 2);
    ssum += __shfl_xor(ssum, 1);
    const float inv = 1.f / ssum;
    for (int u = g; u < T49; u += 8) sc[t][u] *= inv;
  }
  __syncthreads();
  // PV: f = tid (256), 7 t-accumulators per thread; sc reads broadcast
  const float* fs = featT + (size_t)s * T49 * 256;
  float* outp = attended + ((size_t)qs * T49 + tg * 7) * 256;
  float acc[7] = {0.f, 0.f, 0.f, 0.f, 0.f, 0.f, 0.f};
  for (int u = 0; u < T49; ++u) {
    const float v = fs[u * 256 + tid];
#pragma unroll
    for (int i = 0; i < 7; ++i) acc[i] += sc[i][u] * v;
  }
#pragma unroll
  for (int i = 0; i < 7; ++i) outp[(size_t)i * 256 + tid] = acc[i];
}

// ---------------- batched MFMA GRU (r17: column-owned gates + bf16 h) -------
// Combines r11's 1-barrier skeleton (wave owns 16 h-cols j of ALL 3 gates;
// MFMA C/D layout puts all 3 gate pre-acts for (row,j) in one lane -> gate
// math straight from acc regs; h in dual-buffered LDS) with r16's
// single-bf16 h (2-pass MFMA: Ah*Bh + Ah*Bl = 24 MFMA, 4 ds_reads).
// Same quantization points as r16 (absmax 0.0078): only h is bf16.
// 24 blocks x 512 thr, full 16-row M-tile, ONE barrier/step, no ghs.
__global__ __launch_bounds__(512) void gru_mfma(
    const float* __restrict__ gi,   // (375,49,384), includes bi
    const float* __restrict__ wh,   // (384,128) f32
    const float* __restrict__ bh,   // (384)
    float* __restrict__ y,          // (375,49,128) if store_all else (375,128)
    int store_all) {
  __shared__ u16 hah[2][16][136];
  const int tid = threadIdx.x;
  const int lane = tid & 63, wv = tid >> 6;   // 8 waves
  const int r0 = blockIdx.x * 16;
  const int c = lane & 15, rq = lane >> 4;
  const int j = wv * 16 + c;        // h column this lane owns
  const int ko = rq << 3;
  // ---- one-time: Wh fragments (hi/lo) for this wave's 3 gate n-frags ----
  bf16x8v Bhr[3][4], Blr[3][4];
#pragma unroll
  for (int g = 0; g < 3; ++g) {
#pragma unroll
    for (int kk = 0; kk < 4; ++kk) {
      const float* p = wh + (size_t)(g * 128 + j) * 128 + kk * 32 + ko;
      float v[8];
      *(float4*)&v[0] = *(const float4*)p;
      *(float4*)&v[4] = *(const float4*)(p + 4);
      u32 hp[4], lp[4];
      split8(v, hp, lp);
      Bhr[g][kk] = *(bf16x8v*)hp;
      Blr[g][kk] = *(bf16x8v*)lp;
    }
  }
  const float bh0 = bh[j], bh1 = bh[128 + j], bh2 = bh[256 + j];
  int seqs[4];
#pragma unroll
  for (int i = 0; i < 4; ++i) {
    const int s_ = r0 + rq * 4 + i;
    seqs[i] = s_ < B3 ? s_ : B3 - 1;
  }
  for (int i = tid; i < 2 * 16 * 136; i += 512) ((u16*)hah)[i] = 0;
  float hprev[4] = {0.f, 0.f, 0.f, 0.f};
  __syncthreads();
  // preload gi for t=0
  float x0[4], x1[4], x2[4];
#pragma unroll
  for (int i = 0; i < 4; ++i) {
    const float* g = gi + (size_t)seqs[i] * T49 * 384 + j;
    x0[i] = g[0]; x1[i] = g[128]; x2[i] = g[256];
  }
  for (int t = 0; t < T49; ++t) {
    const int pr = t & 1, pw = pr ^ 1;
    // prefetch gi for t+1 (lands under MFMA+gates)
    const int tn = (t + 1 < T49) ? t + 1 : t;
    float y0[4], y1[4], y2[4];
#pragma unroll
    for (int i = 0; i < 4; ++i) {
      const float* g = gi + ((size_t)seqs[i] * T49 + tn) * 384 + j;
      y0[i] = g[0]; y1[i] = g[128]; y2[i] = g[256];
    }
    // A-frags (h bf16) from read buffer
    bf16x8v Ah[4];
#pragma unroll
    for (int kk = 0; kk < 4; ++kk)
      Ah[kk] = *(const bf16x8v*)&hah[pr][c][kk * 32 + ko];
    // 3 gate accumulators (independent chains), 2-pass: h*Wh_hi + h*Wh_lo
    f32x4 aR = {0, 0, 0, 0}, aZ = {0, 0, 0, 0}, aN = {0, 0, 0, 0};
#pragma unroll
    for (int kk = 0; kk < 4; ++kk) {
      aR = __builtin_amdgcn_mfma_f32_16x16x32_bf16(Ah[kk], Bhr[0][kk], aR, 0, 0, 0);
      aZ = __builtin_amdgcn_mfma_f32_16x16x32_bf16(Ah[kk], Bhr[1][kk], aZ, 0, 0, 0);
      aN = __builtin_amdgcn_mfma_f32_16x16x32_bf16(Ah[kk], Bhr[2][kk], aN, 0, 0, 0);
    }
#pragma unroll
    for (int kk = 0; kk < 4; ++kk) {
      aR = __builtin_amdgcn_mfma_f32_16x16x32_bf16(Ah[kk], Blr[0][kk], aR, 0, 0, 0);
      aZ = __builtin_amdgcn_mfma_f32_16x16x32_bf16(Ah[kk], Blr[1][kk], aZ, 0, 0, 0);
      aN = __builtin_amdgcn_mfma_f32_16x16x32_bf16(Ah[kk], Blr[2][kk], aN, 0, 0, 0);
    }
    // gate math directly from acc regs; write h to write-buffer
#pragma unroll
    for (int i = 0; i < 4; ++i) {
      const int row = rq * 4 + i;
      const float r_ = fsigmoid(x0[i] + aR[i] + bh0);
      const float z_ = fsigmoid(x1[i] + aZ[i] + bh1);
      const float n_ = ftanh(x2[i] + r_ * (aN[i] + bh2));
      const float hn = (1.f - z_) * n_ + z_ * hprev[i];
      hprev[i] = hn;
      hah[pw][row][j] = f2b(hn);
      const int seq = r0 + row;
      if (seq < B3) {
        if (store_all) y[((size_t)seq * T49 + t) * 128 + j] = hn;
        else if (t == T49 - 1) y[(size_t)seq * 128 + j] = hn;
      }
    }
    __syncthreads();
#pragma unroll
    for (int i = 0; i < 4; ++i) { x0[i] = y0[i]; x1[i] = y1[i]; x2[i] = y2[i]; }
  }
}

// ---------------- head ----------------
__global__ __launch_bounds__(512) void head_kernel(
    const float* __restrict__ hf, const float* __restrict__ tw,
    const float* __restrict__ tb, float* __restrict__ out) {
  __shared__ float lg[B3];
  const int tid = threadIdx.x;
  if (tid < B3) {
    const float* h = hf + (size_t)tid * 128;
    float acc = tb[0];
    for (int k = 0; k < 128; ++k) acc += h[k] * tw[k];
    lg[tid] = acc;
  }
  __syncthreads();
  if (tid < NQ) {
    float cls[5];
#pragma unroll
    for (int n = 0; n < 5; ++n) {
      float s = 0.f;
#pragma unroll
      for (int k = 0; k < 5; ++k) s += lg[tid * 25 + n * 5 + k];
      cls[n] = s;
    }
    float m = cls[0];
#pragma unroll
    for (int n = 1; n < 5; ++n) m = fmaxf(m, cls[n]);
    float se = 0.f;
#pragma unroll
    for (int n = 0; n < 5; ++n) se += expf(cls[n] - m);
    const float lse = m + logf(se);
#pragma unroll
    for (int n = 0; n < 5; ++n) out[tid * 5 + n] = cls[n] - lse;
  }
}

extern "C" void kernel_launch(void* const* d_in, const int* in_sizes, int n_in,
                              void* d_out, int out_size, void* d_ws,
                              size_t ws_size, hipStream_t stream) {
  (void)in_sizes; (void)n_in; (void)out_size; (void)ws_size;
  const float* support = (const float*)d_in[0];
  const float* query   = (const float*)d_in[1];
  const float* cw1 = (const float*)d_in[2];  const float* cb1 = (const float*)d_in[3];
  const float* cw2 = (const float*)d_in[4];  const float* cb2 = (const float*)d_in[5];
  const float* cw3 = (const float*)d_in[6];  const float* cb3 = (const float*)d_in[7];
  const float* cw4 = (const float*)d_in[8];  const float* cb4 = (const float*)d_in[9];
  const float* g1  = (const float*)d_in[10]; const float* be1 = (const float*)d_in[11];
  const float* g2  = (const float*)d_in[12]; const float* be2 = (const float*)d_in[13];
  const float* g3  = (const float*)d_in[14]; const float* be3 = (const float*)d_in[15];
  const float* g4  = (const float*)d_in[16]; const float* be4 = (const float*)d_in[17];
  const float* aw  = (const float*)d_in[18]; const float* ab  = (const float*)d_in[19];
  const float* wi0 = (const float*)d_in[20]; const float* wh0 = (const float*)d_in[21];
  const float* bi0 = (const float*)d_in[22]; const float* bh0 = (const float*)d_in[23];
  const float* wi1 = (const float*)d_in[24]; const float* wh1 = (const float*)d_in[25];
  const float* bi1 = (const float*)d_in[26]; const float* bh1 = (const float*)d_in[27];
  const float* tw  = (const float*)d_in[28]; const float* tb  = (const float*)d_in[29];

  char* ws = (char*)d_ws;
  float* out = (float*)d_out;
  float* A1    = (float*)(ws + A1_OFF);
  float* X2    = (float*)(ws + X2_OFF);
  float* P2    = (float*)(ws + P2_OFF);
  float* X3    = (float*)(ws + X3_OFF);
  float* P3    = (float*)(ws + P3_OFF);
  float* X4    = (float*)(ws + X4_OFF);
  float* FEATT = (float*)(ws + FEATT_OFF);
  float* PROJ  = (float*)(ws + PROJ_OFF);
  float* ATT   = (float*)(ws + ATT_OFF);
  float* GI    = (float*)(ws + GI_OFF);
  float* Y0    = (float*)(ws + Y0_OFF);
  float* HFIN  = (float*)(ws + HFIN_OFF);
  u16* WBH = (u16*)(ws + WBH_OFF);
  u16* WBL = (u16*)(ws + WBL_OFF);

  // weight conversions (split hi/lo)
  cvt_conv_w_split<<<(64 * 288 + 255) / 256, 256, 0, stream>>>(cw2, WBH + W2_E, WBL + W2_E, 64, 32);
  cvt_conv_w_split<<<(128 * 576 + 255) / 256, 256, 0, stream>>>(cw3, WBH + W3_E, WBL + W3_E, 128, 64);
  cvt_conv_w_split<<<(256 * 1152 + 255) / 256, 256, 0, stream>>>(cw4, WBH + W4_E, WBL + W4_E, 256, 128);
  cvt_split<<<(64 * 256 + 255) / 256, 256, 0, stream>>>(aw, WBH + AW_E, WBL + AW_E, 64 * 256);
  cvt_split<<<(384 * 512 + 255) / 256, 256, 0, stream>>>(wi0, WBH + WI0_E, WBL + WI0_E, 384 * 512);
  cvt_split<<<(384 * 128 + 255) / 256, 256, 0, stream>>>(wi1, WBH + WI1_E, WBL + WI1_E, 384 * 128);

  // ---- encoder ----
  conv1_pool<<<15680, 256, 0, stream>>>(support, query, cw1, cb1, g1, be1, A1);
  // conv2: A1(40,56,56,32) -> X2(40,56,56,64) -> P2(40,28,28,64)
  sgemm<2, 0><<<dim3(1, 1960), 256, 0, stream>>>(
      A1, nullptr, 125440, 288, WBH + W2_E, WBL + W2_E, cb2, g2, be2, X2, 64,
      56, 56, 32, 5);
  maxpool2_f32<<<1960, 256, 0, stream>>>(X2, P2, NB, 56, 56, 64);
  // conv3: P2 -> X3(40,28,28,128) -> P3(40,14,14,128)
  sgemm<2, 0><<<dim3(2, 490), 256, 0, stream>>>(
      P2, nullptr, 31360, 576, WBH + W3_E, WBL + W3_E, cb3, g3, be3, X3, 128,
      28, 28, 64, 6);
  maxpool2_f32<<<980, 256, 0, stream>>>(X3, P3, NB, 28, 28, 128);
  // conv4: P3 -> X4(40,14,14,256) -> FEATT(40,7,7,256)
  sgemm<2, 0><<<dim3(4, 123), 256, 0, stream>>>(
      P3, nullptr, 7840, 1152, WBH + W4_E, WBL + W4_E, cb4, g4, be4, X4, 256,
      14, 14, 128, 7);
  maxpool2_f32<<<490, 256, 0, stream>>>(X4, FEATT, NB, 14, 14, 256);

  // ---- attention ----
  sgemm<0, 1><<<dim3(1, 31), 256, 0, stream>>>(
      FEATT, nullptr, NB * T49, 256, WBH + AW_E, WBL + AW_E, ab, nullptr,
      nullptr, PROJ, 64, 0, 0, 0, 0);
  attention_f32<<<B3 * 7, 256, 0, stream>>>(PROJ, FEATT, ATT);

  // ---- GRU stack ----
  sgemm<1, 1><<<dim3(6, 288), 256, 0, stream>>>(
      ATT, FEATT, B3 * T49, 512, WBH + WI0_E, WBL + WI0_E, bi0, nullptr,
      nullptr, GI, 384, 0, 0, 0, 0);
  gru_mfma<<<24, 512, 0, stream>>>(GI, wh0, bh0, Y0, 1);
  sgemm<0, 1><<<dim3(6, 288), 256, 0, stream>>>(
      Y0, nullptr, B3 * T49, 128, WBH + WI1_E, WBL + WI1_E, bi1, nullptr,
      nullptr, GI, 384, 0, 0, 0, 0);
  gru_mfma<<<24, 512, 0, stream>>>(GI, wh1, bh1, HFIN, 0);

  // ---- head ----
  head_kernel<<<1, 512, 0, stream>>>(HFIN, tw, tb, out);
}

// Round 18
// 370.374 us; speedup vs baseline: 1.0634x; 1.0634x over previous
//
#include <hip/hip_runtime.h>
#include <hip/hip_bf16.h>
#include <math.h>

typedef unsigned short u16;
typedef unsigned int u32;
typedef __attribute__((ext_vector_type(8))) short bf16x8v;
typedef __attribute__((ext_vector_type(4))) float f32x4;

// ---------------- problem constants ----------------
constexpr int NS = 25, NQ = 15, NB = 40;
constexpr int B3 = 375;     // 15*25
constexpr int T49 = 49;
constexpr float BN_INV = 0.9999950000374997f;

// ---------------- workspace layout (BYTES), f32 activations ----------------
constexpr size_t A1_OFF    = 0;            // (40,56,56,32) f32 = 16,056,320
constexpr size_t X2_OFF    = 16056320;     // (40,56,56,64) f32 = 32,112,640
constexpr size_t P2_OFF    = 48168960;     // (40,28,28,64) f32 = 8,028,160
constexpr size_t X3_OFF    = 0;            // (40,28,28,128) f32 = 16,056,320
constexpr size_t P3_OFF    = 56197120;     // (40,14,14,128) f32 = 4,014,080
constexpr size_t X4_OFF    = 16056320;     // (40,14,14,256) f32 = 8,028,160
constexpr size_t FEATT_OFF = 60211200;     // (40,49,256) f32 = 2,007,040
constexpr size_t PROJ_OFF  = 24084480;     // (1960,64) f32 = 501,760
constexpr size_t ATT_OFF   = 24586240;     // (375,49,256) f32 = 18,816,000
constexpr size_t GI_OFF    = 62218240;     // (18375,384) f32 = 28,224,000
constexpr size_t Y0_OFF    = 0;            // (18375,128) f32 = 9,408,000
constexpr size_t HFIN_OFF  = 90442240;     // (375,128) f32 = 192,000
constexpr size_t WBH_OFF   = 91027456;     // bf16-hi arena 649,216 u16
constexpr size_t WBL_OFF   = 92325888;     // bf16-lo arena
// u16-element offsets within each arena (== flat concat offsets):
constexpr size_t W2_E = 0;        // 64*288    = 18,432
constexpr size_t W3_E = 18432;    // 128*576   = 73,728
constexpr size_t W4_E = 92160;    // 256*1152  = 294,912
constexpr size_t AW_E = 387072;   // 64*256    = 16,384
constexpr size_t WI0_E = 403456;  // 384*512   = 196,608
constexpr size_t WI1_E = 600064;  // 384*128   = 49,152
constexpr int CVT_N = 649216;

static __device__ __forceinline__ u16 f2b(float f) {
  __hip_bfloat16 h = __float2bfloat16(f);
  return *reinterpret_cast<u16*>(&h);
}
static __device__ __forceinline__ float b2f(u16 u) {
  return __uint_as_float((u32)u << 16);
}
// split v into hi+lo bf16 pair, packed into u32 words
static __device__ __forceinline__ void split8(const float* v, u32* hp, u32* lp) {
  u16 h[8], l[8];
#pragma unroll
  for (int j = 0; j < 8; ++j) {
    const u16 hb = f2b(v[j]);
    h[j] = hb;
    l[j] = f2b(v[j] - b2f(hb));
  }
#pragma unroll
  for (int j = 0; j < 4; ++j) {
    hp[j] = (u32)h[2 * j] | ((u32)h[2 * j + 1] << 16);
    lp[j] = (u32)l[2 * j] | ((u32)l[2 * j + 1] << 16);
  }
}
// fast sigmoid / tanh (exp2+rcp intrinsics; err ~1e-6)
constexpr float LOG2E = 1.4426950408889634f;
static __device__ __forceinline__ float fsigmoid(float x) {
  return __builtin_amdgcn_rcpf(1.f + __builtin_amdgcn_exp2f(-x * LOG2E));
}
static __device__ __forceinline__ float ftanh(float x) {
  return 1.f - 2.f * __builtin_amdgcn_rcpf(__builtin_amdgcn_exp2f(x * (2.f * LOG2E)) + 1.f);
}

// ---------------- fused weight converter (r18: was 6 launches, now 1) -------
// Arena layout == flat concat, so dst index = i; only src mapping branches.
// Conv segments remap OIHW -> [oc][(ky*3+kx)*IC+ic].
__global__ void cvt_all(const float* __restrict__ cw2, const float* __restrict__ cw3,
                        const float* __restrict__ cw4, const float* __restrict__ aw,
                        const float* __restrict__ wi0, const float* __restrict__ wi1,
                        u16* __restrict__ oh, u16* __restrict__ ol) {
  const int i = blockIdx.x * 256 + threadIdx.x;
  if (i >= CVT_N) return;
  float v;
  if (i < (int)W3_E) {              // w2: OC=64 IC=32
    const int l = i, oc = l / 288, rem = l - oc * 288, e = rem >> 5, ic = rem & 31;
    v = cw2[((size_t)(oc * 32 + ic) * 3 + e / 3) * 3 + e % 3];
  } else if (i < (int)W4_E) {       // w3: OC=128 IC=64
    const int l = i - (int)W3_E, oc = l / 576, rem = l - oc * 576, e = rem >> 6, ic = rem & 63;
    v = cw3[((size_t)(oc * 64 + ic) * 3 + e / 3) * 3 + e % 3];
  } else if (i < (int)AW_E) {       // w4: OC=256 IC=128
    const int l = i - (int)W4_E, oc = l / 1152, rem = l - oc * 1152, e = rem >> 7, ic = rem & 127;
    v = cw4[((size_t)(oc * 128 + ic) * 3 + e / 3) * 3 + e % 3];
  } else if (i < (int)WI0_E) {
    v = aw[i - (int)AW_E];
  } else if (i < (int)WI1_E) {
    v = wi0[i - (int)WI0_E];
  } else {
    v = wi1[i - (int)WI1_E];
  }
  const u16 h = f2b(v);
  oh[i] = h;
  ol[i] = f2b(v - b2f(h));
}

// ---------------- fused conv1(s2)+BN+ReLU+pool2, f32 out NHWC ----------------
__global__ __launch_bounds__(256) void conv1_pool(
    const float* __restrict__ support, const float* __restrict__ query,
    const float* __restrict__ w1, const float* __restrict__ cb1,
    const float* __restrict__ g1, const float* __restrict__ be1,
    float* __restrict__ out) {
  __shared__ float wl[288], scl[32], shl[32], cbl[32];
  const int tid = threadIdx.x;
  for (int l = tid; l < 288; l += 256) wl[l] = w1[l];  // FIX(r5): strided, 288>256
  if (tid < 32) { scl[tid] = g1[tid] * BN_INV; shl[tid] = be1[tid]; cbl[tid] = cb1[tid]; }
  __syncthreads();
  const int oc = tid & 31;
  const int p = blockIdx.x * 8 + (tid >> 5);   // 0 .. 125439 = (b,oy,ox)
  const int ox = p % 56, oy = (p / 56) % 56, b = p / 3136;
  const float* in_b = (b < NS) ? (support + (size_t)b * 50176)
                               : (query + (size_t)(b - NS) * 50176);
  const int iy0 = 4 * oy - 1, ix0 = 4 * ox - 1;
  float pat[5][5];
#pragma unroll
  for (int dy = 0; dy < 5; ++dy) {
    const int iy = iy0 + dy;
#pragma unroll
    for (int dx = 0; dx < 5; ++dx) {
      const int ix = ix0 + dx;
      pat[dy][dx] = (iy >= 0 && iy < 224 && ix >= 0 && ix < 224)
                        ? in_b[(size_t)iy * 224 + ix] : 0.f;
    }
  }
  const float* wp = &wl[oc * 9];
  float mx = 0.f;  // post-ReLU values >= 0
#pragma unroll
  for (int py = 0; py < 2; ++py)
#pragma unroll
    for (int px = 0; px < 2; ++px) {
      float acc = 0.f;
#pragma unroll
      for (int ky = 0; ky < 3; ++ky)
#pragma unroll
        for (int kx = 0; kx < 3; ++kx)
          acc += pat[2 * py + ky][2 * px + kx] * wp[ky * 3 + kx];
      float v = (acc + cbl[oc]) * scl[oc] + shl[oc];
      mx = fmaxf(mx, v);
    }
  out[(size_t)p * 32 + oc] = mx;
}

// ---------------- f32 NHWC maxpool 2x2 ----------------
__global__ void maxpool2_f32(const float* __restrict__ X, float* __restrict__ Y,
                             int Bn, int H, int W, int C) {
  const int OH = H >> 1, OW = W >> 1;
  const int cpr = C >> 2;
  const int chunks = Bn * OH * OW * cpr;
  for (int i = blockIdx.x * blockDim.x + threadIdx.x; i < chunks;
       i += gridDim.x * blockDim.x) {
    const int c4 = i % cpr, m = i / cpr;
    const int ox = m % OW, oy = (m / OW) % OH, b = m / (OW * OH);
    const size_t base = (((size_t)b * H + 2 * oy) * W + 2 * ox) * C + (c4 << 2);
    const float4 r0 = *(const float4*)&X[base];
    const float4 r1 = *(const float4*)&X[base + C];
    const float4 r2 = *(const float4*)&X[base + (size_t)W * C];
    const float4 r3 = *(const float4*)&X[base + (size_t)W * C + C];
    float4 o;
    o.x = fmaxf(fmaxf(r0.x, r1.x), fmaxf(r2.x, r3.x));
    o.y = fmaxf(fmaxf(r0.y, r1.y), fmaxf(r2.y, r3.y));
    o.z = fmaxf(fmaxf(r0.z, r1.z), fmaxf(r2.z, r3.z));
    o.w = fmaxf(fmaxf(r0.w, r1.w), fmaxf(r2.w, r3.w));
    *(float4*)&Y[(size_t)m * C + (c4 << 2)] = o;
  }
}

// ---------------- split-bf16 MFMA GEMM: C = epi(A @ W^T) --------------------
// 3-pass Dekker: acc += Ah*Wh + Ah*Wl + Al*Wh  (error ~1.6e-5 relative)
// AMODE 0: A f32 (M x K) contiguous.
// AMODE 1: K=512 concat gather: k<256 -> A(=ATT f32), else A2(=FEATT f32) qrep.
// AMODE 2: implicit im2col from A = NHWC f32 (Bn,H,W,IC); K = 9*IC; pad=1.
// EPI 0: f32 out = relu((acc+p0[n])*p1[n]*BN_INV + p2[n]).  EPI 1: f32 out = acc+p0[n].
template <int AMODE, int EPI>
__global__ __launch_bounds__(256) void sgemm(
    const float* __restrict__ A, const float* __restrict__ A2, int M, int K,
    const u16* __restrict__ Bh, const u16* __restrict__ Bl,
    const float* __restrict__ p0, const float* __restrict__ p1,
    const float* __restrict__ p2, float* __restrict__ Cout, int ldc,
    int H, int W, int IC, int icb) {
  __shared__ u16 Ash[64][72], Asl[64][72];
  __shared__ u16 Bsh[64][72], Bsl[64][72];
  const int tid = threadIdx.x;
  const int lane = tid & 63, wv = tid >> 6;
  const int wy = wv >> 1, wx = wv & 1;
  const int n0 = blockIdx.x * 64, m0 = blockIdx.y * 64;
  f32x4 acc[2][2] = {{{0, 0, 0, 0}, {0, 0, 0, 0}}, {{0, 0, 0, 0}, {0, 0, 0, 0}}};
  for (int k0 = 0; k0 < K; k0 += 64) {
    // ---- stage A (split f32 -> hi/lo bf16) ----
#pragma unroll
    for (int s = 0; s < 2; ++s) {
      const int c = s * 256 + tid;
      const int row = c >> 3, kc = (c & 7) << 3;
      const int gm = m0 + row, gk = k0 + kc;
      float4 x0 = {0, 0, 0, 0}, x1 = {0, 0, 0, 0};
      if (AMODE == 0) {
        if (gm < M && gk < K) {
          const float* p = A + (size_t)gm * K + gk;
          x0 = *(const float4*)p; x1 = *(const float4*)(p + 4);
        }
      } else if (AMODE == 1) {
        if (gm < M) {
          const float* p;
          if (gk < 256) {
            p = A + (size_t)gm * 256 + gk;
          } else {
            const int b = gm / T49, t = gm % T49, q = b / NS;
            p = A2 + (((size_t)(NS + q) * T49 + t) << 8) + (gk - 256);
          }
          x0 = *(const float4*)p; x1 = *(const float4*)(p + 4);
        }
      } else {  // implicit im2col
        if (gm < M && gk < K) {
          const int ox = gm % W, t_ = gm / W;
          const int oy = t_ % H, b = t_ / H;
          const int e = gk >> icb, ic = gk & (IC - 1);
          const int ky = e / 3, kx = e - 3 * (e / 3);
          const int iy = oy + ky - 1, ix = ox + kx - 1;
          if (iy >= 0 && iy < H && ix >= 0 && ix < W) {
            const float* p = A + (((size_t)b * H + iy) * W + ix) * IC + ic;
            x0 = *(const float4*)p; x1 = *(const float4*)(p + 4);
          }
        }
      }
      float v[8] = {x0.x, x0.y, x0.z, x0.w, x1.x, x1.y, x1.z, x1.w};
      u32 hp[4], lp[4];
      split8(v, hp, lp);
      *(uint4*)&Ash[row][kc] = *(uint4*)hp;
      *(uint4*)&Asl[row][kc] = *(uint4*)lp;
    }
    // ---- stage B (pre-split weights) ----
#pragma unroll
    for (int s = 0; s < 2; ++s) {
      const int c = s * 256 + tid;
      const int row = c >> 3, kc = (c & 7) << 3;
      const int gk = k0 + kc;
      uint4 vh = {0u, 0u, 0u, 0u}, vl = {0u, 0u, 0u, 0u};
      if (gk < K) {
        vh = *(const uint4*)&Bh[(size_t)(n0 + row) * K + gk];
        vl = *(const uint4*)&Bl[(size_t)(n0 + row) * K + gk];
      }
      *(uint4*)&Bsh[row][kc] = vh;
      *(uint4*)&Bsl[row][kc] = vl;
    }
    __syncthreads();
#pragma unroll
    for (int kk = 0; kk < 64; kk += 32) {
      const int ko = kk + ((lane >> 4) << 3);
      const int ra0 = wy * 32 + (lane & 15), ra1 = ra0 + 16;
      const int rb0 = wx * 32 + (lane & 15), rb1 = rb0 + 16;
      bf16x8v a0h = *(const bf16x8v*)&Ash[ra0][ko];
      bf16x8v a1h = *(const bf16x8v*)&Ash[ra1][ko];
      bf16x8v b0h = *(const bf16x8v*)&Bsh[rb0][ko];
      bf16x8v b1h = *(const bf16x8v*)&Bsh[rb1][ko];
      bf16x8v a0l = *(const bf16x8v*)&Asl[ra0][ko];
      bf16x8v a1l = *(const bf16x8v*)&Asl[ra1][ko];
      bf16x8v b0l = *(const bf16x8v*)&Bsl[rb0][ko];
      bf16x8v b1l = *(const bf16x8v*)&Bsl[rb1][ko];
      acc[0][0] = __builtin_amdgcn_mfma_f32_16x16x32_bf16(a0h, b0h, acc[0][0], 0, 0, 0);
      acc[0][1] = __builtin_amdgcn_mfma_f32_16x16x32_bf16(a0h, b1h, acc[0][1], 0, 0, 0);
      acc[1][0] = __builtin_amdgcn_mfma_f32_16x16x32_bf16(a1h, b0h, acc[1][0], 0, 0, 0);
      acc[1][1] = __builtin_amdgcn_mfma_f32_16x16x32_bf16(a1h, b1h, acc[1][1], 0, 0, 0);
      acc[0][0] = __builtin_amdgcn_mfma_f32_16x16x32_bf16(a0h, b0l, acc[0][0], 0, 0, 0);
      acc[0][1] = __builtin_amdgcn_mfma_f32_16x16x32_bf16(a0h, b1l, acc[0][1], 0, 0, 0);
      acc[1][0] = __builtin_amdgcn_mfma_f32_16x16x32_bf16(a1h, b0l, acc[1][0], 0, 0, 0);
      acc[1][1] = __builtin_amdgcn_mfma_f32_16x16x32_bf16(a1h, b1l, acc[1][1], 0, 0, 0);
      acc[0][0] = __builtin_amdgcn_mfma_f32_16x16x32_bf16(a0l, b0h, acc[0][0], 0, 0, 0);
      acc[0][1] = __builtin_amdgcn_mfma_f32_16x16x32_bf16(a0l, b1h, acc[0][1], 0, 0, 0);
      acc[1][0] = __builtin_amdgcn_mfma_f32_16x16x32_bf16(a1l, b0h, acc[1][0], 0, 0, 0);
      acc[1][1] = __builtin_amdgcn_mfma_f32_16x16x32_bf16(a1l, b1h, acc[1][1], 0, 0, 0);
    }
    __syncthreads();
  }
  // ---- epilogue (f32 out) ----
#pragma unroll
  for (int r = 0; r < 2; ++r) {
#pragma unroll
    for (int c = 0; c < 2; ++c) {
      const int gn = n0 + wx * 32 + c * 16 + (lane & 15);
      float sc0 = 0.f, sh0 = 0.f;
      if (EPI == 0) { sc0 = p1[gn] * BN_INV; sh0 = p2[gn]; }
#pragma unroll
      for (int i = 0; i < 4; ++i) {
        const int gm = m0 + wy * 32 + r * 16 + ((lane >> 4) << 2) + i;
        if (gm >= M) continue;
        const float a = acc[r][c][i];
        if (EPI == 0) {
          Cout[(size_t)gm * ldc + gn] = fmaxf((a + p0[gn]) * sc0 + sh0, 0.f);
        } else {
          Cout[(size_t)gm * ldc + gn] = a + p0[gn];
        }
      }
    }
  }
}

// ---------------- fused attention, block = (q,s,t-group of 7) ---------------
// r10: 256-thread blocks, parallel 8-lane softmax, padded WqT.
__global__ __launch_bounds__(256) void attention_f32(
    const float* __restrict__ proj, const float* __restrict__ featT,
    float* __restrict__ attended) {
  __shared__ float WqT[64][9];    // [h][tloc], 7 used, pad 9 -> conflict-free
  __shared__ float WhT[64][51];   // [h][u], odd pad -> conflict-free
  __shared__ float sc[7][64];
  const int bid = blockIdx.x;
  const int qs = bid / 7, tg = bid - 7 * qs;
  const int q = qs / NS, s = qs - NS * q;
  const int tid = threadIdx.x;
  const float* pq = proj + ((size_t)(NS + q) * T49 + tg * 7) * 64;
  const float* ph = proj + (size_t)s * T49 * 64;
  for (int l = tid; l < 7 * 64; l += 256) WqT[l & 63][l >> 6] = pq[l];
  for (int l = tid; l < T49 * 64; l += 256) WhT[l & 63][l >> 6] = ph[l];
  __syncthreads();
  // scores: 343 (t,u) pairs over 256 threads, 4-acc ILP h-loop
  constexpr float C2LOG2E = 2.8853900817779268f;
  for (int e = tid; e < 343; e += 256) {
    const int tl = e / 49, u = e - 49 * tl;
    float a0 = 0.f, a1 = 0.f, a2 = 0.f, a3 = 0.f;
#pragma unroll
    for (int h = 0; h < 64; h += 4) {
      const float p0 = WqT[h + 0][tl] * WhT[h + 0][u];
      const float p1 = WqT[h + 1][tl] * WhT[h + 1][u];
      const float p2 = WqT[h + 2][tl] * WhT[h + 2][u];
      const float p3 = WqT[h + 3][tl] * WhT[h + 3][u];
      a0 += 1.f - 2.f * __builtin_amdgcn_rcpf(__builtin_amdgcn_exp2f(p0 * C2LOG2E) + 1.f);
      a1 += 1.f - 2.f * __builtin_amdgcn_rcpf(__builtin_amdgcn_exp2f(p1 * C2LOG2E) + 1.f);
      a2 += 1.f - 2.f * __builtin_amdgcn_rcpf(__builtin_amdgcn_exp2f(p2 * C2LOG2E) + 1.f);
      a3 += 1.f - 2.f * __builtin_amdgcn_rcpf(__builtin_amdgcn_exp2f(p3 * C2LOG2E) + 1.f);
    }
    sc[tl][u] = (a0 + a1) + (a2 + a3);
  }
  __syncthreads();
  // parallel softmax: 8 lanes per row, all 56 lanes in wave 0
  if (tid < 56) {
    const int t = tid >> 3, g = tid & 7;
    float m = -3.4e38f;
    for (int u = g; u < T49; u += 8) m = fmaxf(m, sc[t][u]);
    m = fmaxf(m, __shfl_xor(m, 4));
    m = fmaxf(m, __shfl_xor(m, 2));
    m = fmaxf(m, __shfl_xor(m, 1));
    float ssum = 0.f;
    for (int u = g; u < T49; u += 8) {
      const float e = __builtin_amdgcn_exp2f((sc[t][u] - m) * LOG2E);
      sc[t][u] = e; ssum += e;
    }
    ssum += __shfl_xor(ssum, 4);
    ssum += __shfl_xor(ssum, 2);
    ssum += __shfl_xor(ssum, 1);
    const float inv = 1.f / ssum;
    for (int u = g; u < T49; u += 8) sc[t][u] *= inv;
  }
  __syncthreads();
  // PV: f = tid (256), 7 t-accumulators per thread; sc reads broadcast
  const float* fs = featT + (size_t)s * T49 * 256;
  float* outp = attended + ((size_t)qs * T49 + tg * 7) * 256;
  float acc[7] = {0.f, 0.f, 0.f, 0.f, 0.f, 0.f, 0.f};
  for (int u = 0; u < T49; ++u) {
    const float v = fs[u * 256 + tid];
#pragma unroll
    for (int i = 0; i < 7; ++i) acc[i] += sc[i][u] * v;
  }
#pragma unroll
  for (int i = 0; i < 7; ++i) outp[(size_t)i * 256 + tid] = acc[i];
}

// ---------------- batched MFMA GRU (r16 version — best measured: 53.5us) ----
// SPB=8, 47 blocks, 512 thr, gi prefetch, fast gates, single-bf16 h
// (2-pass MFMA: Ah*Bh + Ah*Bl), weights hi/lo. absmax 0.0078 (4x margin).
// r17's 24-block column-owned variant regressed (60us) — fewer CUs lose more
// than the saved barrier; this structure is the measured local optimum.
constexpr int SPB = 8;
__global__ __launch_bounds__(512) void gru_mfma(
    const float* __restrict__ gi,   // (375,49,384), includes bi
    const float* __restrict__ wh,   // (384,128) f32
    const float* __restrict__ bh,   // (384)
    float* __restrict__ y,          // (375,49,128) if store_all else (375,128)
    int store_all) {
  __shared__ u16 hah[16][136];
  __shared__ float ghs[SPB][384];
  __shared__ float hfl[SPB][128];
  const int tid = threadIdx.x;
  const int lane = tid & 63, wv = tid >> 6;   // 8 waves
  const int r0 = blockIdx.x * SPB;
  // ---- one-time: load + split Wh fragments into registers ----
  bf16x8v Bhr[3][4], Blr[3][4];
#pragma unroll
  for (int f = 0; f < 3; ++f) {
    const int n = (wv * 3 + f) * 16 + (lane & 15);
#pragma unroll
    for (int kk = 0; kk < 4; ++kk) {
      const int k = kk * 32 + ((lane >> 4) << 3);
      const float* p = wh + (size_t)n * 128 + k;
      float v[8];
      *(float4*)&v[0] = *(const float4*)p;
      *(float4*)&v[4] = *(const float4*)(p + 4);
      u32 hp[4], lp[4];
      split8(v, hp, lp);
      Bhr[f][kk] = *(bf16x8v*)hp;
      Blr[f][kk] = *(bf16x8v*)lp;
    }
  }
  const int row0 = tid >> 7, j0 = tid & 127;
  const int row1 = (512 + tid) >> 7, j1 = tid & 127;
  int sq0 = r0 + row0; if (sq0 >= B3) sq0 = B3 - 1;
  int sq1 = r0 + row1; if (sq1 >= B3) sq1 = B3 - 1;
  const float bhr0 = bh[j0], bhz0 = bh[128 + j0], bhn0 = bh[256 + j0];
  const float bhr1 = bh[j1], bhz1 = bh[128 + j1], bhn1 = bh[256 + j1];
  const float* gib0 = gi + (size_t)sq0 * T49 * 384;
  const float* gib1 = gi + (size_t)sq1 * T49 * 384;
  for (int i = tid; i < 16 * 136; i += 512) hah[i / 136][i % 136] = 0;
  for (int i = tid; i < SPB * 128; i += 512) hfl[i >> 7][i & 127] = 0.f;
  __syncthreads();
  const int ar = lane & 15, ko = (lane >> 4) << 3;
  float xr0c = gib0[j0], xz0c = gib0[128 + j0], xn0c = gib0[256 + j0];
  float xr1c = gib1[j1], xz1c = gib1[128 + j1], xn1c = gib1[256 + j1];
  for (int t = 0; t < T49; ++t) {
    const int tn = (t + 1 < T49) ? t + 1 : t;
    const float* g0n = gib0 + (size_t)tn * 384;
    const float* g1n = gib1 + (size_t)tn * 384;
    const float xr0n = g0n[j0], xz0n = g0n[128 + j0], xn0n = g0n[256 + j0];
    const float xr1n = g1n[j1], xz1n = g1n[128 + j1], xn1n = g1n[256 + j1];
    bf16x8v Ah[4];
#pragma unroll
    for (int kk = 0; kk < 4; ++kk)
      Ah[kk] = *(const bf16x8v*)&hah[ar][kk * 32 + ko];
#pragma unroll
    for (int f = 0; f < 3; ++f) {
      f32x4 acc = {0, 0, 0, 0};
#pragma unroll
      for (int kk = 0; kk < 4; ++kk)
        acc = __builtin_amdgcn_mfma_f32_16x16x32_bf16(Ah[kk], Bhr[f][kk], acc, 0, 0, 0);
#pragma unroll
      for (int kk = 0; kk < 4; ++kk)
        acc = __builtin_amdgcn_mfma_f32_16x16x32_bf16(Ah[kk], Blr[f][kk], acc, 0, 0, 0);
      const int nc = (wv * 3 + f) * 16 + (lane & 15);
      const int rb = (lane >> 4) << 2;
      if (rb < SPB) {
#pragma unroll
        for (int i = 0; i < 4; ++i) ghs[rb + i][nc] = acc[i];
      }
    }
    __syncthreads();
    {
      const float r_ = fsigmoid(xr0c + ghs[row0][j0] + bhr0);
      const float z_ = fsigmoid(xz0c + ghs[row0][128 + j0] + bhz0);
      const float n_ = ftanh(xn0c + r_ * (ghs[row0][256 + j0] + bhn0));
      const float hn = (1.f - z_) * n_ + z_ * hfl[row0][j0];
      hfl[row0][j0] = hn;
      hah[row0][j0] = f2b(hn);
      if (r0 + row0 < B3) {
        if (store_all) y[((size_t)(r0 + row0) * T49 + t) * 128 + j0] = hn;
        else if (t == T49 - 1) y[(size_t)(r0 + row0) * 128 + j0] = hn;
      }
    }
    {
      const float r_ = fsigmoid(xr1c + ghs[row1][j1] + bhr1);
      const float z_ = fsigmoid(xz1c + ghs[row1][128 + j1] + bhz1);
      const float n_ = ftanh(xn1c + r_ * (ghs[row1][256 + j1] + bhn1));
      const float hn = (1.f - z_) * n_ + z_ * hfl[row1][j1];
      hfl[row1][j1] = hn;
      hah[row1][j1] = f2b(hn);
      if (r0 + row1 < B3) {
        if (store_all) y[((size_t)(r0 + row1) * T49 + t) * 128 + j1] = hn;
        else if (t == T49 - 1) y[(size_t)(r0 + row1) * 128 + j1] = hn;
      }
    }
    __syncthreads();
    xr0c = xr0n; xz0c = xz0n; xn0c = xn0n;
    xr1c = xr1n; xz1c = xz1n; xn1c = xn1n;
  }
}

// ---------------- head ----------------
__global__ __launch_bounds__(512) void head_kernel(
    const float* __restrict__ hf, const float* __restrict__ tw,
    const float* __restrict__ tb, float* __restrict__ out) {
  __shared__ float lg[B3];
  const int tid = threadIdx.x;
  if (tid < B3) {
    const float* h = hf + (size_t)tid * 128;
    float acc = tb[0];
    for (int k = 0; k < 128; ++k) acc += h[k] * tw[k];
    lg[tid] = acc;
  }
  __syncthreads();
  if (tid < NQ) {
    float cls[5];
#pragma unroll
    for (int n = 0; n < 5; ++n) {
      float s = 0.f;
#pragma unroll
      for (int k = 0; k < 5; ++k) s += lg[tid * 25 + n * 5 + k];
      cls[n] = s;
    }
    float m = cls[0];
#pragma unroll
    for (int n = 1; n < 5; ++n) m = fmaxf(m, cls[n]);
    float se = 0.f;
#pragma unroll
    for (int n = 0; n < 5; ++n) se += expf(cls[n] - m);
    const float lse = m + logf(se);
#pragma unroll
    for (int n = 0; n < 5; ++n) out[tid * 5 + n] = cls[n] - lse;
  }
}

extern "C" void kernel_launch(void* const* d_in, const int* in_sizes, int n_in,
                              void* d_out, int out_size, void* d_ws,
                              size_t ws_size, hipStream_t stream) {
  (void)in_sizes; (void)n_in; (void)out_size; (void)ws_size;
  const float* support = (const float*)d_in[0];
  const float* query   = (const float*)d_in[1];
  const float* cw1 = (const float*)d_in[2];  const float* cb1 = (const float*)d_in[3];
  const float* cw2 = (const float*)d_in[4];  const float* cb2 = (const float*)d_in[5];
  const float* cw3 = (const float*)d_in[6];  const float* cb3 = (const float*)d_in[7];
  const float* cw4 = (const float*)d_in[8];  const float* cb4 = (const float*)d_in[9];
  const float* g1  = (const float*)d_in[10]; const float* be1 = (const float*)d_in[11];
  const float* g2  = (const float*)d_in[12]; const float* be2 = (const float*)d_in[13];
  const float* g3  = (const float*)d_in[14]; const float* be3 = (const float*)d_in[15];
  const float* g4  = (const float*)d_in[16]; const float* be4 = (const float*)d_in[17];
  const float* aw  = (const float*)d_in[18]; const float* ab  = (const float*)d_in[19];
  const float* wi0 = (const float*)d_in[20]; const float* wh0 = (const float*)d_in[21];
  const float* bi0 = (const float*)d_in[22]; const float* bh0 = (const float*)d_in[23];
  const float* wi1 = (const float*)d_in[24]; const float* wh1 = (const float*)d_in[25];
  const float* bi1 = (const float*)d_in[26]; const float* bh1 = (const float*)d_in[27];
  const float* tw  = (const float*)d_in[28]; const float* tb  = (const float*)d_in[29];

  char* ws = (char*)d_ws;
  float* out = (float*)d_out;
  float* A1    = (float*)(ws + A1_OFF);
  float* X2    = (float*)(ws + X2_OFF);
  float* P2    = (float*)(ws + P2_OFF);
  float* X3    = (float*)(ws + X3_OFF);
  float* P3    = (float*)(ws + P3_OFF);
  float* X4    = (float*)(ws + X4_OFF);
  float* FEATT = (float*)(ws + FEATT_OFF);
  float* PROJ  = (float*)(ws + PROJ_OFF);
  float* ATT   = (float*)(ws + ATT_OFF);
  float* GI    = (float*)(ws + GI_OFF);
  float* Y0    = (float*)(ws + Y0_OFF);
  float* HFIN  = (float*)(ws + HFIN_OFF);
  u16* WBH = (u16*)(ws + WBH_OFF);
  u16* WBL = (u16*)(ws + WBL_OFF);

  // weight conversions (single fused launch; was 6)
  cvt_all<<<(CVT_N + 255) / 256, 256, 0, stream>>>(cw2, cw3, cw4, aw, wi0, wi1, WBH, WBL);

  // ---- encoder ----
  conv1_pool<<<15680, 256, 0, stream>>>(support, query, cw1, cb1, g1, be1, A1);
  // conv2: A1(40,56,56,32) -> X2(40,56,56,64) -> P2(40,28,28,64)
  sgemm<2, 0><<<dim3(1, 1960), 256, 0, stream>>>(
      A1, nullptr, 125440, 288, WBH + W2_E, WBL + W2_E, cb2, g2, be2, X2, 64,
      56, 56, 32, 5);
  maxpool2_f32<<<1960, 256, 0, stream>>>(X2, P2, NB, 56, 56, 64);
  // conv3: P2 -> X3(40,28,28,128) -> P3(40,14,14,128)
  sgemm<2, 0><<<dim3(2, 490), 256, 0, stream>>>(
      P2, nullptr, 31360, 576, WBH + W3_E, WBL + W3_E, cb3, g3, be3, X3, 128,
      28, 28, 64, 6);
  maxpool2_f32<<<980, 256, 0, stream>>>(X3, P3, NB, 28, 28, 128);
  // conv4: P3 -> X4(40,14,14,256) -> FEATT(40,7,7,256)
  sgemm<2, 0><<<dim3(4, 123), 256, 0, stream>>>(
      P3, nullptr, 7840, 1152, WBH + W4_E, WBL + W4_E, cb4, g4, be4, X4, 256,
      14, 14, 128, 7);
  maxpool2_f32<<<490, 256, 0, stream>>>(X4, FEATT, NB, 14, 14, 256);

  // ---- attention ----
  sgemm<0, 1><<<dim3(1, 31), 256, 0, stream>>>(
      FEATT, nullptr, NB * T49, 256, WBH + AW_E, WBL + AW_E, ab, nullptr,
      nullptr, PROJ, 64, 0, 0, 0, 0);
  attention_f32<<<B3 * 7, 256, 0, stream>>>(PROJ, FEATT, ATT);

  // ---- GRU stack ----
  sgemm<1, 1><<<dim3(6, 288), 256, 0, stream>>>(
      ATT, FEATT, B3 * T49, 512, WBH + WI0_E, WBL + WI0_E, bi0, nullptr,
      nullptr, GI, 384, 0, 0, 0, 0);
  gru_mfma<<<47, 512, 0, stream>>>(GI, wh0, bh0, Y0, 1);
  sgemm<0, 1><<<dim3(6, 288), 256, 0, stream>>>(
      Y0, nullptr, B3 * T49, 128, WBH + WI1_E, WBL + WI1_E, bi1, nullptr,
      nullptr, GI, 384, 0, 0, 0, 0);
  gru_mfma<<<47, 512, 0, stream>>>(GI, wh1, bh1, HFIN, 0);

  // ---- head ----
  head_kernel<<<1, 512, 0, stream>>>(HFIN, tw, tb, out);
}

// Round 19
// 367.467 us; speedup vs baseline: 1.0718x; 1.0079x over previous
//
#include <hip/hip_runtime.h>
#include <hip/hip_bf16.h>
#include <math.h>

typedef unsigned short u16;
typedef unsigned int u32;
typedef __attribute__((ext_vector_type(8))) short bf16x8v;
typedef __attribute__((ext_vector_type(4))) float f32x4;

// ---------------- problem constants ----------------
constexpr int NS = 25, NQ = 15, NB = 40;
constexpr int B3 = 375;     // 15*25
constexpr int T49 = 49;
constexpr float BN_INV = 0.9999950000374997f;

// ---------------- workspace layout (BYTES) ----------------------------------
// r19: activations consumed by sgemm are stored as TWO bf16 planes (hi,lo),
// split ONCE at the producer (numerically identical to the old per-tile
// split8). Lifetimes (verified):
//  conv1->A1h/l | conv2: A1->X2 f32 | pool2: X2->P2h/l | conv3: P2->X3 (A1 dead)
//  pool3: X3->P3h/l | conv4: P3->X4 (X3 dead) | pool4: X4->FEATTh/l
//  proj: FEATT->PROJ (X4 dead) | attn: PROJ,FEATT->ATTh/l (X2 dead)
//  gemm0: ATT,FEATT->GI | gru0: GI->Y0h/l (PROJ dead) | gemm1: Y0->GI | gru1->HFIN
constexpr size_t A1H_OFF    = 0;           // u16 4,014,080 el = 8,028,160 B
constexpr size_t A1L_OFF    = 8028160;
constexpr size_t X2_OFF     = 16056320;    // f32 32,112,640 B
constexpr size_t P2H_OFF    = 48168960;    // u16 4,014,080 B
constexpr size_t P2L_OFF    = 52183040;
constexpr size_t X3_OFF     = 0;           // f32 16,056,320 B
constexpr size_t P3H_OFF    = 56197120;    // u16 2,007,040 B
constexpr size_t P3L_OFF    = 58204160;
constexpr size_t X4_OFF     = 0;           // f32 8,028,160 B
constexpr size_t FEATTH_OFF = 60211200;    // u16 1,003,520 B
constexpr size_t FEATTL_OFF = 61214720;
constexpr size_t PROJ_OFF   = 0;           // f32 501,760 B
constexpr size_t ATTH_OFF   = 16056320;    // u16 9,408,000 B
constexpr size_t ATTL_OFF   = 25464320;
constexpr size_t GI_OFF     = 62218240;    // f32 28,224,000 B
constexpr size_t Y0H_OFF    = 0;           // u16 4,704,000 B
constexpr size_t Y0L_OFF    = 4704000;
constexpr size_t HFIN_OFF   = 90442240;    // f32 192,000 B
constexpr size_t WBH_OFF    = 91027456;    // bf16-hi weight arena
constexpr size_t WBL_OFF    = 92325888;    // bf16-lo weight arena
// u16-element offsets within each weight arena (== flat concat offsets):
constexpr size_t W2_E = 0;
constexpr size_t W3_E = 18432;
constexpr size_t W4_E = 92160;
constexpr size_t AW_E = 387072;
constexpr size_t WI0_E = 403456;
constexpr size_t WI1_E = 600064;
constexpr int CVT_N = 649216;

static __device__ __forceinline__ u16 f2b(float f) {
  __hip_bfloat16 h = __float2bfloat16(f);
  return *reinterpret_cast<u16*>(&h);
}
static __device__ __forceinline__ float b2f(u16 u) {
  return __uint_as_float((u32)u << 16);
}
// fast sigmoid / tanh (exp2+rcp intrinsics; err ~1e-6)
constexpr float LOG2E = 1.4426950408889634f;
static __device__ __forceinline__ float fsigmoid(float x) {
  return __builtin_amdgcn_rcpf(1.f + __builtin_amdgcn_exp2f(-x * LOG2E));
}
static __device__ __forceinline__ float ftanh(float x) {
  return 1.f - 2.f * __builtin_amdgcn_rcpf(__builtin_amdgcn_exp2f(x * (2.f * LOG2E)) + 1.f);
}
// split v into hi+lo bf16 pair, packed into u32 words (weights/gru use)
static __device__ __forceinline__ void split8(const float* v, u32* hp, u32* lp) {
  u16 h[8], l[8];
#pragma unroll
  for (int j = 0; j < 8; ++j) {
    const u16 hb = f2b(v[j]);
    h[j] = hb;
    l[j] = f2b(v[j] - b2f(hb));
  }
#pragma unroll
  for (int j = 0; j < 4; ++j) {
    hp[j] = (u32)h[2 * j] | ((u32)h[2 * j + 1] << 16);
    lp[j] = (u32)l[2 * j] | ((u32)l[2 * j + 1] << 16);
  }
}

// ---------------- fused weight converter (1 launch) ----------------
__global__ void cvt_all(const float* __restrict__ cw2, const float* __restrict__ cw3,
                        const float* __restrict__ cw4, const float* __restrict__ aw,
                        const float* __restrict__ wi0, const float* __restrict__ wi1,
                        u16* __restrict__ oh, u16* __restrict__ ol) {
  const int i = blockIdx.x * 256 + threadIdx.x;
  if (i >= CVT_N) return;
  float v;
  if (i < (int)W3_E) {              // w2: OC=64 IC=32
    const int l = i, oc = l / 288, rem = l - oc * 288, e = rem >> 5, ic = rem & 31;
    v = cw2[((size_t)(oc * 32 + ic) * 3 + e / 3) * 3 + e % 3];
  } else if (i < (int)W4_E) {       // w3: OC=128 IC=64
    const int l = i - (int)W3_E, oc = l / 576, rem = l - oc * 576, e = rem >> 6, ic = rem & 63;
    v = cw3[((size_t)(oc * 64 + ic) * 3 + e / 3) * 3 + e % 3];
  } else if (i < (int)AW_E) {       // w4: OC=256 IC=128
    const int l = i - (int)W4_E, oc = l / 1152, rem = l - oc * 1152, e = rem >> 7, ic = rem & 127;
    v = cw4[((size_t)(oc * 128 + ic) * 3 + e / 3) * 3 + e % 3];
  } else if (i < (int)WI0_E) {
    v = aw[i - (int)AW_E];
  } else if (i < (int)WI1_E) {
    v = wi0[i - (int)WI0_E];
  } else {
    v = wi1[i - (int)WI1_E];
  }
  const u16 h = f2b(v);
  oh[i] = h;
  ol[i] = f2b(v - b2f(h));
}

// ---------------- fused conv1(s2)+BN+ReLU+pool2 -> bf16 hi/lo NHWC ----------
__global__ __launch_bounds__(256) void conv1_pool(
    const float* __restrict__ support, const float* __restrict__ query,
    const float* __restrict__ w1, const float* __restrict__ cb1,
    const float* __restrict__ g1, const float* __restrict__ be1,
    u16* __restrict__ outh, u16* __restrict__ outl) {
  __shared__ float wl[288], scl[32], shl[32], cbl[32];
  const int tid = threadIdx.x;
  for (int l = tid; l < 288; l += 256) wl[l] = w1[l];  // FIX(r5): strided
  if (tid < 32) { scl[tid] = g1[tid] * BN_INV; shl[tid] = be1[tid]; cbl[tid] = cb1[tid]; }
  __syncthreads();
  const int oc = tid & 31;
  const int p = blockIdx.x * 8 + (tid >> 5);
  const int ox = p % 56, oy = (p / 56) % 56, b = p / 3136;
  const float* in_b = (b < NS) ? (support + (size_t)b * 50176)
                               : (query + (size_t)(b - NS) * 50176);
  const int iy0 = 4 * oy - 1, ix0 = 4 * ox - 1;
  float pat[5][5];
#pragma unroll
  for (int dy = 0; dy < 5; ++dy) {
    const int iy = iy0 + dy;
#pragma unroll
    for (int dx = 0; dx < 5; ++dx) {
      const int ix = ix0 + dx;
      pat[dy][dx] = (iy >= 0 && iy < 224 && ix >= 0 && ix < 224)
                        ? in_b[(size_t)iy * 224 + ix] : 0.f;
    }
  }
  const float* wp = &wl[oc * 9];
  float mx = 0.f;
#pragma unroll
  for (int py = 0; py < 2; ++py)
#pragma unroll
    for (int px = 0; px < 2; ++px) {
      float acc = 0.f;
#pragma unroll
      for (int ky = 0; ky < 3; ++ky)
#pragma unroll
        for (int kx = 0; kx < 3; ++kx)
          acc += pat[2 * py + ky][2 * px + kx] * wp[ky * 3 + kx];
      float v = (acc + cbl[oc]) * scl[oc] + shl[oc];
      mx = fmaxf(mx, v);
    }
  const u16 h = f2b(mx);
  outh[(size_t)p * 32 + oc] = h;
  outl[(size_t)p * 32 + oc] = f2b(mx - b2f(h));
}

// ---------------- f32 NHWC maxpool 2x2 -> bf16 hi/lo planes -----------------
__global__ void maxpool2_split(const float* __restrict__ X, u16* __restrict__ Yh,
                               u16* __restrict__ Yl, int Bn, int H, int W, int C) {
  const int OH = H >> 1, OW = W >> 1;
  const int cpr = C >> 2;
  const int chunks = Bn * OH * OW * cpr;
  for (int i = blockIdx.x * blockDim.x + threadIdx.x; i < chunks;
       i += gridDim.x * blockDim.x) {
    const int c4 = i % cpr, m = i / cpr;
    const int ox = m % OW, oy = (m / OW) % OH, b = m / (OW * OH);
    const size_t base = (((size_t)b * H + 2 * oy) * W + 2 * ox) * C + (c4 << 2);
    const float4 r0 = *(const float4*)&X[base];
    const float4 r1 = *(const float4*)&X[base + C];
    const float4 r2 = *(const float4*)&X[base + (size_t)W * C];
    const float4 r3 = *(const float4*)&X[base + (size_t)W * C + C];
    float o[4];
    o[0] = fmaxf(fmaxf(r0.x, r1.x), fmaxf(r2.x, r3.x));
    o[1] = fmaxf(fmaxf(r0.y, r1.y), fmaxf(r2.y, r3.y));
    o[2] = fmaxf(fmaxf(r0.z, r1.z), fmaxf(r2.z, r3.z));
    o[3] = fmaxf(fmaxf(r0.w, r1.w), fmaxf(r2.w, r3.w));
    u16 hh[4], ll[4];
#pragma unroll
    for (int j = 0; j < 4; ++j) {
      hh[j] = f2b(o[j]);
      ll[j] = f2b(o[j] - b2f(hh[j]));
    }
    const size_t off = (size_t)m * C + (c4 << 2);
    uint2 vh, vl;
    vh.x = (u32)hh[0] | ((u32)hh[1] << 16); vh.y = (u32)hh[2] | ((u32)hh[3] << 16);
    vl.x = (u32)ll[0] | ((u32)ll[1] << 16); vl.y = (u32)ll[2] | ((u32)ll[3] << 16);
    *(uint2*)&Yh[off] = vh;
    *(uint2*)&Yl[off] = vl;
  }
}

// ---------------- split-bf16 MFMA GEMM: C = epi(A @ W^T) --------------------
// A now arrives PRE-SPLIT as hi/lo bf16 planes -> stage A is pure uint4 copy
// (was: f32 loads + ~50-VALU split8 per 8 elems, re-done 9x for im2col).
// 3-pass Dekker semantics preserved: acc += Ah*Bh + Ah*Bl + Al*Bh.
// AMODE 0: (Ah,Al) M x K contiguous.  AMODE 1: K=512 gather ATT|FEATT planes.
// AMODE 2: implicit im2col from NHWC planes (Bn,H,W,IC); K=9*IC; pad=1.
template <int AMODE, int EPI>
__global__ __launch_bounds__(256) void sgemm(
    const u16* __restrict__ Ah, const u16* __restrict__ Al,
    const u16* __restrict__ A2h, const u16* __restrict__ A2l, int M, int K,
    const u16* __restrict__ Bh, const u16* __restrict__ Bl,
    const float* __restrict__ p0, const float* __restrict__ p1,
    const float* __restrict__ p2, float* __restrict__ Cout, int ldc,
    int H, int W, int IC, int icb) {
  __shared__ u16 Ash[64][72], Asl[64][72];
  __shared__ u16 Bsh[64][72], Bsl[64][72];
  const int tid = threadIdx.x;
  const int lane = tid & 63, wv = tid >> 6;
  const int wy = wv >> 1, wx = wv & 1;
  const int n0 = blockIdx.x * 64, m0 = blockIdx.y * 64;
  f32x4 acc[2][2] = {{{0, 0, 0, 0}, {0, 0, 0, 0}}, {{0, 0, 0, 0}, {0, 0, 0, 0}}};
  for (int k0 = 0; k0 < K; k0 += 64) {
    // ---- stage A (pure copies from pre-split planes) ----
#pragma unroll
    for (int s = 0; s < 2; ++s) {
      const int cc = s * 256 + tid;
      const int row = cc >> 3, kc = (cc & 7) << 3;
      const int gm = m0 + row, gk = k0 + kc;
      uint4 vh = {0u, 0u, 0u, 0u}, vl = {0u, 0u, 0u, 0u};
      if (AMODE == 0) {
        if (gm < M && gk < K) {
          const size_t idx = (size_t)gm * K + gk;
          vh = *(const uint4*)&Ah[idx];
          vl = *(const uint4*)&Al[idx];
        }
      } else if (AMODE == 1) {
        if (gm < M) {
          size_t idx;
          const u16 *ph_, *pl_;
          if (gk < 256) {
            idx = (size_t)gm * 256 + gk; ph_ = Ah; pl_ = Al;
          } else {
            const int b = gm / T49, t = gm % T49, q = b / NS;
            idx = (((size_t)(NS + q) * T49 + t) << 8) + (gk - 256);
            ph_ = A2h; pl_ = A2l;
          }
          vh = *(const uint4*)&ph_[idx];
          vl = *(const uint4*)&pl_[idx];
        }
      } else {  // implicit im2col
        if (gm < M && gk < K) {
          const int ox = gm % W, t_ = gm / W;
          const int oy = t_ % H, b = t_ / H;
          const int e = gk >> icb, ic = gk & (IC - 1);
          const int ky = e / 3, kx = e - 3 * (e / 3);
          const int iy = oy + ky - 1, ix = ox + kx - 1;
          if (iy >= 0 && iy < H && ix >= 0 && ix < W) {
            const size_t idx = (((size_t)b * H + iy) * W + ix) * IC + ic;
            vh = *(const uint4*)&Ah[idx];
            vl = *(const uint4*)&Al[idx];
          }
        }
      }
      *(uint4*)&Ash[row][kc] = vh;
      *(uint4*)&Asl[row][kc] = vl;
    }
    // ---- stage B (pre-split weights) ----
#pragma unroll
    for (int s = 0; s < 2; ++s) {
      const int cc = s * 256 + tid;
      const int row = cc >> 3, kc = (cc & 7) << 3;
      const int gk = k0 + kc;
      uint4 vh = {0u, 0u, 0u, 0u}, vl = {0u, 0u, 0u, 0u};
      if (gk < K) {
        vh = *(const uint4*)&Bh[(size_t)(n0 + row) * K + gk];
        vl = *(const uint4*)&Bl[(size_t)(n0 + row) * K + gk];
      }
      *(uint4*)&Bsh[row][kc] = vh;
      *(uint4*)&Bsl[row][kc] = vl;
    }
    __syncthreads();
#pragma unroll
    for (int kk = 0; kk < 64; kk += 32) {
      const int ko = kk + ((lane >> 4) << 3);
      const int ra0 = wy * 32 + (lane & 15), ra1 = ra0 + 16;
      const int rb0 = wx * 32 + (lane & 15), rb1 = rb0 + 16;
      bf16x8v a0h = *(const bf16x8v*)&Ash[ra0][ko];
      bf16x8v a1h = *(const bf16x8v*)&Ash[ra1][ko];
      bf16x8v b0h = *(const bf16x8v*)&Bsh[rb0][ko];
      bf16x8v b1h = *(const bf16x8v*)&Bsh[rb1][ko];
      bf16x8v a0l = *(const bf16x8v*)&Asl[ra0][ko];
      bf16x8v a1l = *(const bf16x8v*)&Asl[ra1][ko];
      bf16x8v b0l = *(const bf16x8v*)&Bsl[rb0][ko];
      bf16x8v b1l = *(const bf16x8v*)&Bsl[rb1][ko];
      acc[0][0] = __builtin_amdgcn_mfma_f32_16x16x32_bf16(a0h, b0h, acc[0][0], 0, 0, 0);
      acc[0][1] = __builtin_amdgcn_mfma_f32_16x16x32_bf16(a0h, b1h, acc[0][1], 0, 0, 0);
      acc[1][0] = __builtin_amdgcn_mfma_f32_16x16x32_bf16(a1h, b0h, acc[1][0], 0, 0, 0);
      acc[1][1] = __builtin_amdgcn_mfma_f32_16x16x32_bf16(a1h, b1h, acc[1][1], 0, 0, 0);
      acc[0][0] = __builtin_amdgcn_mfma_f32_16x16x32_bf16(a0h, b0l, acc[0][0], 0, 0, 0);
      acc[0][1] = __builtin_amdgcn_mfma_f32_16x16x32_bf16(a0h, b1l, acc[0][1], 0, 0, 0);
      acc[1][0] = __builtin_amdgcn_mfma_f32_16x16x32_bf16(a1h, b0l, acc[1][0], 0, 0, 0);
      acc[1][1] = __builtin_amdgcn_mfma_f32_16x16x32_bf16(a1h, b1l, acc[1][1], 0, 0, 0);
      acc[0][0] = __builtin_amdgcn_mfma_f32_16x16x32_bf16(a0l, b0h, acc[0][0], 0, 0, 0);
      acc[0][1] = __builtin_amdgcn_mfma_f32_16x16x32_bf16(a0l, b1h, acc[0][1], 0, 0, 0);
      acc[1][0] = __builtin_amdgcn_mfma_f32_16x16x32_bf16(a1l, b0h, acc[1][0], 0, 0, 0);
      acc[1][1] = __builtin_amdgcn_mfma_f32_16x16x32_bf16(a1l, b1h, acc[1][1], 0, 0, 0);
    }
    __syncthreads();
  }
  // ---- epilogue (f32 out) ----
#pragma unroll
  for (int r = 0; r < 2; ++r) {
#pragma unroll
    for (int cI = 0; cI < 2; ++cI) {
      const int gn = n0 + wx * 32 + cI * 16 + (lane & 15);
      float sc0 = 0.f, sh0 = 0.f;
      if (EPI == 0) { sc0 = p1[gn] * BN_INV; sh0 = p2[gn]; }
#pragma unroll
      for (int i = 0; i < 4; ++i) {
        const int gm = m0 + wy * 32 + r * 16 + ((lane >> 4) << 2) + i;
        if (gm >= M) continue;
        const float a = acc[r][cI][i];
        if (EPI == 0) {
          Cout[(size_t)gm * ldc + gn] = fmaxf((a + p0[gn]) * sc0 + sh0, 0.f);
        } else {
          Cout[(size_t)gm * ldc + gn] = a + p0[gn];
        }
      }
    }
  }
}

// ---------------- fused attention, block = (q,s,t-group of 7) ---------------
// r19: V read reconstructs hi+lo (delta ~1e-5); ATT written as hi/lo planes.
__global__ __launch_bounds__(256) void attention_f32(
    const float* __restrict__ proj, const u16* __restrict__ featTh,
    const u16* __restrict__ featTl, u16* __restrict__ atth,
    u16* __restrict__ attl) {
  __shared__ float WqT[64][9];
  __shared__ float WhT[64][51];
  __shared__ float sc[7][64];
  const int bid = blockIdx.x;
  const int qs = bid / 7, tg = bid - 7 * qs;
  const int q = qs / NS, s = qs - NS * q;
  const int tid = threadIdx.x;
  const float* pq = proj + ((size_t)(NS + q) * T49 + tg * 7) * 64;
  const float* ph = proj + (size_t)s * T49 * 64;
  for (int l = tid; l < 7 * 64; l += 256) WqT[l & 63][l >> 6] = pq[l];
  for (int l = tid; l < T49 * 64; l += 256) WhT[l & 63][l >> 6] = ph[l];
  __syncthreads();
  constexpr float C2LOG2E = 2.8853900817779268f;
  for (int e = tid; e < 343; e += 256) {
    const int tl = e / 49, u = e - 49 * tl;
    float a0 = 0.f, a1 = 0.f, a2 = 0.f, a3 = 0.f;
#pragma unroll
    for (int h = 0; h < 64; h += 4) {
      const float p0 = WqT[h + 0][tl] * WhT[h + 0][u];
      const float p1 = WqT[h + 1][tl] * WhT[h + 1][u];
      const float p2 = WqT[h + 2][tl] * WhT[h + 2][u];
      const float p3 = WqT[h + 3][tl] * WhT[h + 3][u];
      a0 += 1.f - 2.f * __builtin_amdgcn_rcpf(__builtin_amdgcn_exp2f(p0 * C2LOG2E) + 1.f);
      a1 += 1.f - 2.f * __builtin_amdgcn_rcpf(__builtin_amdgcn_exp2f(p1 * C2LOG2E) + 1.f);
      a2 += 1.f - 2.f * __builtin_amdgcn_rcpf(__builtin_amdgcn_exp2f(p2 * C2LOG2E) + 1.f);
      a3 += 1.f - 2.f * __builtin_amdgcn_rcpf(__builtin_amdgcn_exp2f(p3 * C2LOG2E) + 1.f);
    }
    sc[tl][u] = (a0 + a1) + (a2 + a3);
  }
  __syncthreads();
  if (tid < 56) {
    const int t = tid >> 3, g = tid & 7;
    float m = -3.4e38f;
    for (int u = g; u < T49; u += 8) m = fmaxf(m, sc[t][u]);
    m = fmaxf(m, __shfl_xor(m, 4));
    m = fmaxf(m, __shfl_xor(m, 2));
    m = fmaxf(m, __shfl_xor(m, 1));
    float ssum = 0.f;
    for (int u = g; u < T49; u += 8) {
      const float e = __builtin_amdgcn_exp2f((sc[t][u] - m) * LOG2E);
      sc[t][u] = e; ssum += e;
    }
    ssum += __shfl_xor(ssum, 4);
    ssum += __shfl_xor(ssum, 2);
    ssum += __shfl_xor(ssum, 1);
    const float inv = 1.f / ssum;
    for (int u = g; u < T49; u += 8) sc[t][u] *= inv;
  }
  __syncthreads();
  const u16* fsh = featTh + (size_t)s * T49 * 256;
  const u16* fsl = featTl + (size_t)s * T49 * 256;
  const size_t obase = ((size_t)qs * T49 + tg * 7) * 256;
  float acc[7] = {0.f, 0.f, 0.f, 0.f, 0.f, 0.f, 0.f};
  for (int u = 0; u < T49; ++u) {
    const float v = b2f(fsh[u * 256 + tid]) + b2f(fsl[u * 256 + tid]);
#pragma unroll
    for (int i = 0; i < 7; ++i) acc[i] += sc[i][u] * v;
  }
#pragma unroll
  for (int i = 0; i < 7; ++i) {
    const float a = acc[i];
    const u16 h = f2b(a);
    atth[obase + (size_t)i * 256 + tid] = h;
    attl[obase + (size_t)i * 256 + tid] = f2b(a - b2f(h));
  }
}

// ---------------- batched MFMA GRU (r16 structure, 53.5us measured) ---------
// store_all writes Y0 as hi/lo bf16 planes (hi == value already computed for
// hah; lo is one extra sub+cvt) so gemm1 stages by pure copy.
constexpr int SPB = 8;
__global__ __launch_bounds__(512) void gru_mfma(
    const float* __restrict__ gi,   // (375,49,384), includes bi
    const float* __restrict__ wh,   // (384,128) f32
    const float* __restrict__ bh,   // (384)
    u16* __restrict__ yh, u16* __restrict__ yl,  // (375,49,128) if store_all
    float* __restrict__ hfin,                    // (375,128) if !store_all
    int store_all) {
  __shared__ u16 hah[16][136];
  __shared__ float ghs[SPB][384];
  __shared__ float hfl[SPB][128];
  const int tid = threadIdx.x;
  const int lane = tid & 63, wv = tid >> 6;   // 8 waves
  const int r0 = blockIdx.x * SPB;
  bf16x8v Bhr[3][4], Blr[3][4];
#pragma unroll
  for (int f = 0; f < 3; ++f) {
    const int n = (wv * 3 + f) * 16 + (lane & 15);
#pragma unroll
    for (int kk = 0; kk < 4; ++kk) {
      const int k = kk * 32 + ((lane >> 4) << 3);
      const float* p = wh + (size_t)n * 128 + k;
      float v[8];
      *(float4*)&v[0] = *(const float4*)p;
      *(float4*)&v[4] = *(const float4*)(p + 4);
      u32 hp[4], lp[4];
      split8(v, hp, lp);
      Bhr[f][kk] = *(bf16x8v*)hp;
      Blr[f][kk] = *(bf16x8v*)lp;
    }
  }
  const int row0 = tid >> 7, j0 = tid & 127;
  const int row1 = (512 + tid) >> 7, j1 = tid & 127;
  int sq0 = r0 + row0; if (sq0 >= B3) sq0 = B3 - 1;
  int sq1 = r0 + row1; if (sq1 >= B3) sq1 = B3 - 1;
  const float bhr0 = bh[j0], bhz0 = bh[128 + j0], bhn0 = bh[256 + j0];
  const float bhr1 = bh[j1], bhz1 = bh[128 + j1], bhn1 = bh[256 + j1];
  const float* gib0 = gi + (size_t)sq0 * T49 * 384;
  const float* gib1 = gi + (size_t)sq1 * T49 * 384;
  for (int i = tid; i < 16 * 136; i += 512) hah[i / 136][i % 136] = 0;
  for (int i = tid; i < SPB * 128; i += 512) hfl[i >> 7][i & 127] = 0.f;
  __syncthreads();
  const int ar = lane & 15, ko = (lane >> 4) << 3;
  float xr0c = gib0[j0], xz0c = gib0[128 + j0], xn0c = gib0[256 + j0];
  float xr1c = gib1[j1], xz1c = gib1[128 + j1], xn1c = gib1[256 + j1];
  for (int t = 0; t < T49; ++t) {
    const int tn = (t + 1 < T49) ? t + 1 : t;
    const float* g0n = gib0 + (size_t)tn * 384;
    const float* g1n = gib1 + (size_t)tn * 384;
    const float xr0n = g0n[j0], xz0n = g0n[128 + j0], xn0n = g0n[256 + j0];
    const float xr1n = g1n[j1], xz1n = g1n[128 + j1], xn1n = g1n[256 + j1];
    bf16x8v Ah[4];
#pragma unroll
    for (int kk = 0; kk < 4; ++kk)
      Ah[kk] = *(const bf16x8v*)&hah[ar][kk * 32 + ko];
#pragma unroll
    for (int f = 0; f < 3; ++f) {
      f32x4 acc = {0, 0, 0, 0};
#pragma unroll
      for (int kk = 0; kk < 4; ++kk)
        acc = __builtin_amdgcn_mfma_f32_16x16x32_bf16(Ah[kk], Bhr[f][kk], acc, 0, 0, 0);
#pragma unroll
      for (int kk = 0; kk < 4; ++kk)
        acc = __builtin_amdgcn_mfma_f32_16x16x32_bf16(Ah[kk], Blr[f][kk], acc, 0, 0, 0);
      const int nc = (wv * 3 + f) * 16 + (lane & 15);
      const int rb = (lane >> 4) << 2;
      if (rb < SPB) {
#pragma unroll
        for (int i = 0; i < 4; ++i) ghs[rb + i][nc] = acc[i];
      }
    }
    __syncthreads();
    {
      const float r_ = fsigmoid(xr0c + ghs[row0][j0] + bhr0);
      const float z_ = fsigmoid(xz0c + ghs[row0][128 + j0] + bhz0);
      const float n_ = ftanh(xn0c + r_ * (ghs[row0][256 + j0] + bhn0));
      const float hn = (1.f - z_) * n_ + z_ * hfl[row0][j0];
      hfl[row0][j0] = hn;
      const u16 hb = f2b(hn);
      hah[row0][j0] = hb;
      if (r0 + row0 < B3) {
        if (store_all) {
          const size_t o = ((size_t)(r0 + row0) * T49 + t) * 128 + j0;
          yh[o] = hb;
          yl[o] = f2b(hn - b2f(hb));
        } else if (t == T49 - 1) {
          hfin[(size_t)(r0 + row0) * 128 + j0] = hn;
        }
      }
    }
    {
      const float r_ = fsigmoid(xr1c + ghs[row1][j1] + bhr1);
      const float z_ = fsigmoid(xz1c + ghs[row1][128 + j1] + bhz1);
      const float n_ = ftanh(xn1c + r_ * (ghs[row1][256 + j1] + bhn1));
      const float hn = (1.f - z_) * n_ + z_ * hfl[row1][j1];
      hfl[row1][j1] = hn;
      const u16 hb = f2b(hn);
      hah[row1][j1] = hb;
      if (r0 + row1 < B3) {
        if (store_all) {
          const size_t o = ((size_t)(r0 + row1) * T49 + t) * 128 + j1;
          yh[o] = hb;
          yl[o] = f2b(hn - b2f(hb));
        } else if (t == T49 - 1) {
          hfin[(size_t)(r0 + row1) * 128 + j1] = hn;
        }
      }
    }
    __syncthreads();
    xr0c = xr0n; xz0c = xz0n; xn0c = xn0n;
    xr1c = xr1n; xz1c = xz1n; xn1c = xn1n;
  }
}

// ---------------- head ----------------
__global__ __launch_bounds__(512) void head_kernel(
    const float* __restrict__ hf, const float* __restrict__ tw,
    const float* __restrict__ tb, float* __restrict__ out) {
  __shared__ float lg[B3];
  const int tid = threadIdx.x;
  if (tid < B3) {
    const float* h = hf + (size_t)tid * 128;
    float acc = tb[0];
    for (int k = 0; k < 128; ++k) acc += h[k] * tw[k];
    lg[tid] = acc;
  }
  __syncthreads();
  if (tid < NQ) {
    float cls[5];
#pragma unroll
    for (int n = 0; n < 5; ++n) {
      float s = 0.f;
#pragma unroll
      for (int k = 0; k < 5; ++k) s += lg[tid * 25 + n * 5 + k];
      cls[n] = s;
    }
    float m = cls[0];
#pragma unroll
    for (int n = 1; n < 5; ++n) m = fmaxf(m, cls[n]);
    float se = 0.f;
#pragma unroll
    for (int n = 0; n < 5; ++n) se += expf(cls[n] - m);
    const float lse = m + logf(se);
#pragma unroll
    for (int n = 0; n < 5; ++n) out[tid * 5 + n] = cls[n] - lse;
  }
}

extern "C" void kernel_launch(void* const* d_in, const int* in_sizes, int n_in,
                              void* d_out, int out_size, void* d_ws,
                              size_t ws_size, hipStream_t stream) {
  (void)in_sizes; (void)n_in; (void)out_size; (void)ws_size;
  const float* support = (const float*)d_in[0];
  const float* query   = (const float*)d_in[1];
  const float* cw1 = (const float*)d_in[2];  const float* cb1 = (const float*)d_in[3];
  const float* cw2 = (const float*)d_in[4];  const float* cb2 = (const float*)d_in[5];
  const float* cw3 = (const float*)d_in[6];  const float* cb3 = (const float*)d_in[7];
  const float* cw4 = (const float*)d_in[8];  const float* cb4 = (const float*)d_in[9];
  const float* g1  = (const float*)d_in[10]; const float* be1 = (const float*)d_in[11];
  const float* g2  = (const float*)d_in[12]; const float* be2 = (const float*)d_in[13];
  const float* g3  = (const float*)d_in[14]; const float* be3 = (const float*)d_in[15];
  const float* g4  = (const float*)d_in[16]; const float* be4 = (const float*)d_in[17];
  const float* aw  = (const float*)d_in[18]; const float* ab  = (const float*)d_in[19];
  const float* wi0 = (const float*)d_in[20]; const float* wh0 = (const float*)d_in[21];
  const float* bi0 = (const float*)d_in[22]; const float* bh0 = (const float*)d_in[23];
  const float* wi1 = (const float*)d_in[24]; const float* wh1 = (const float*)d_in[25];
  const float* bi1 = (const float*)d_in[26]; const float* bh1 = (const float*)d_in[27];
  const float* tw  = (const float*)d_in[28]; const float* tb  = (const float*)d_in[29];

  char* ws = (char*)d_ws;
  float* out = (float*)d_out;
  u16* A1H    = (u16*)(ws + A1H_OFF);
  u16* A1L    = (u16*)(ws + A1L_OFF);
  float* X2   = (float*)(ws + X2_OFF);
  u16* P2H    = (u16*)(ws + P2H_OFF);
  u16* P2L    = (u16*)(ws + P2L_OFF);
  float* X3   = (float*)(ws + X3_OFF);
  u16* P3H    = (u16*)(ws + P3H_OFF);
  u16* P3L    = (u16*)(ws + P3L_OFF);
  float* X4   = (float*)(ws + X4_OFF);
  u16* FEATTH = (u16*)(ws + FEATTH_OFF);
  u16* FEATTL = (u16*)(ws + FEATTL_OFF);
  float* PROJ = (float*)(ws + PROJ_OFF);
  u16* ATTH   = (u16*)(ws + ATTH_OFF);
  u16* ATTL   = (u16*)(ws + ATTL_OFF);
  float* GI   = (float*)(ws + GI_OFF);
  u16* Y0H    = (u16*)(ws + Y0H_OFF);
  u16* Y0L    = (u16*)(ws + Y0L_OFF);
  float* HFIN = (float*)(ws + HFIN_OFF);
  u16* WBH = (u16*)(ws + WBH_OFF);
  u16* WBL = (u16*)(ws + WBL_OFF);

  // weight conversions (single fused launch)
  cvt_all<<<(CVT_N + 255) / 256, 256, 0, stream>>>(cw2, cw3, cw4, aw, wi0, wi1, WBH, WBL);

  // ---- encoder ----
  conv1_pool<<<15680, 256, 0, stream>>>(support, query, cw1, cb1, g1, be1, A1H, A1L);
  // conv2: A1(40,56,56,32 planes) -> X2 f32 -> P2 planes
  sgemm<2, 0><<<dim3(1, 1960), 256, 0, stream>>>(
      A1H, A1L, nullptr, nullptr, 125440, 288, WBH + W2_E, WBL + W2_E,
      cb2, g2, be2, X2, 64, 56, 56, 32, 5);
  maxpool2_split<<<1960, 256, 0, stream>>>(X2, P2H, P2L, NB, 56, 56, 64);
  // conv3: P2 -> X3 -> P3
  sgemm<2, 0><<<dim3(2, 490), 256, 0, stream>>>(
      P2H, P2L, nullptr, nullptr, 31360, 576, WBH + W3_E, WBL + W3_E,
      cb3, g3, be3, X3, 128, 28, 28, 64, 6);
  maxpool2_split<<<980, 256, 0, stream>>>(X3, P3H, P3L, NB, 28, 28, 128);
  // conv4: P3 -> X4 -> FEATT
  sgemm<2, 0><<<dim3(4, 123), 256, 0, stream>>>(
      P3H, P3L, nullptr, nullptr, 7840, 1152, WBH + W4_E, WBL + W4_E,
      cb4, g4, be4, X4, 256, 14, 14, 128, 7);
  maxpool2_split<<<490, 256, 0, stream>>>(X4, FEATTH, FEATTL, NB, 14, 14, 256);

  // ---- attention ----
  sgemm<0, 1><<<dim3(1, 31), 256, 0, stream>>>(
      FEATTH, FEATTL, nullptr, nullptr, NB * T49, 256, WBH + AW_E, WBL + AW_E,
      ab, nullptr, nullptr, PROJ, 64, 0, 0, 0, 0);
  attention_f32<<<B3 * 7, 256, 0, stream>>>(PROJ, FEATTH, FEATTL, ATTH, ATTL);

  // ---- GRU stack ----
  sgemm<1, 1><<<dim3(6, 288), 256, 0, stream>>>(
      ATTH, ATTL, FEATTH, FEATTL, B3 * T49, 512, WBH + WI0_E, WBL + WI0_E,
      bi0, nullptr, nullptr, GI, 384, 0, 0, 0, 0);
  gru_mfma<<<47, 512, 0, stream>>>(GI, wh0, bh0, Y0H, Y0L, nullptr, 1);
  sgemm<0, 1><<<dim3(6, 288), 256, 0, stream>>>(
      Y0H, Y0L, nullptr, nullptr, B3 * T49, 128, WBH + WI1_E, WBL + WI1_E,
      bi1, nullptr, nullptr, GI, 384, 0, 0, 0, 0);
  gru_mfma<<<47, 512, 0, stream>>>(GI, wh1, bh1, nullptr, nullptr, HFIN, 0);

  // ---- head ----
  head_kernel<<<1, 512, 0, stream>>>(HFIN, tw, tb, out);
}